// Round 1
// baseline (504.529 us; speedup 1.0000x reference)
//
#include <hip/hip_runtime.h>
#include <hip/hip_bf16.h>

typedef __hip_bfloat16 bf16;
typedef __attribute__((ext_vector_type(8))) __bf16 bf16x8;   // 8 bf16 = 4 VGPRs (MFMA A/B frag)
typedef __attribute__((ext_vector_type(4))) float f32x4;     // MFMA C/D frag
typedef __attribute__((ext_vector_type(4))) float f4;        // indexable float4

// ---------------------------------------------------------------------------
// Downsample 128x128 -> 32x32 (align_corners=False, scale 4 => avg of the
// 2x2 block at rows/cols {4i+1,4i+2}), then ReLU, write bf16 [B*1024][256].
// block: (b, out-row i, channel-chunk of 32). 2048 blocks x 256 thr.
// ---------------------------------------------------------------------------
__global__ __launch_bounds__(256) void downsample_kernel(const float* __restrict__ src,
                                                         bf16* __restrict__ dst)
{
    __shared__ float o[32][33];
    int bid = blockIdx.x;
    int cc = bid & 7, i = (bid >> 3) & 31, b = bid >> 8;
    int t = threadIdx.x;
#pragma unroll
    for (int p = 0; p < 4; ++p) {
        int id = p * 256 + t;
        int c = id >> 5, j = id & 31;
        const float* r = src + ((size_t)(b * 256 + cc * 32 + c) * 128 + 4 * i + 1) * 128 + 4 * j;
        float4 r1 = *(const float4*)r;
        float4 r2 = *(const float4*)(r + 128);
        o[c][j] = 0.25f * (r1.y + r1.z + r2.y + r2.z);
    }
    __syncthreads();
#pragma unroll
    for (int p = 0; p < 4; ++p) {
        int id = p * 256 + t;
        int j = id >> 5, c = id & 31;
        dst[(size_t)(b * 1024 + i * 32 + j) * 256 + cc * 32 + c] = (bf16)fmaxf(o[c][j], 0.f);
    }
}

// ---------------------------------------------------------------------------
// Weight transpose+cast: WT[n][k] = bf16(W[k][n])
// ---------------------------------------------------------------------------
__global__ void wtrans_kernel(const float* __restrict__ W, bf16* __restrict__ WT, int K, int N)
{
    int idx = blockIdx.x * 256 + threadIdx.x;
    if (idx >= K * N) return;
    int n = idx / K, k = idx % K;
    WT[idx] = (bf16)W[(size_t)k * N + n];
}

// ---------------------------------------------------------------------------
// CPB MLP: table[L][2] -> relu(@w1[2][512]+b1) @ w2[512][8]+b2 -> out[h][L]
// ---------------------------------------------------------------------------
__global__ __launch_bounds__(256) void cpb_kernel(const float* __restrict__ tab,
    const float* __restrict__ w1, const float* __restrict__ b1,
    const float* __restrict__ w2, const float* __restrict__ b2,
    float* __restrict__ outp, int L)
{
    int l = blockIdx.x * 256 + threadIdx.x;
    if (l >= L) return;
    float t0 = tab[2 * l], t1 = tab[2 * l + 1];
    float acc[8];
#pragma unroll
    for (int hh = 0; hh < 8; ++hh) acc[hh] = b2[hh];
    for (int j = 0; j < 512; ++j) {
        float hv = fmaxf(t0 * w1[j] + t1 * w1[512 + j] + b1[j], 0.f);
#pragma unroll
        for (int hh = 0; hh < 8; ++hh) acc[hh] += hv * w2[j * 8 + hh];
    }
#pragma unroll
    for (int hh = 0; hh < 8; ++hh) outp[(size_t)hh * L + l] = acc[hh];
}

// ---------------------------------------------------------------------------
// Generic bf16 MFMA GEMM: C[M][N] = act(A[M][K] @ BT[N][K]^T + bias) (+resid)
// 128x128 tile, BK=32, 4 waves (2x2), each wave 64x64 (4x4 16x16 frags).
// act: 0 none, 1 exact gelu.  Writes Cb (bf16) if non-null else Cf (f32).
// ---------------------------------------------------------------------------
__global__ __launch_bounds__(256) void gemm_bt(
    const bf16* __restrict__ A, const bf16* __restrict__ BT,
    const float* __restrict__ bias, bf16* __restrict__ Cb, float* __restrict__ Cf,
    const bf16* __restrict__ resid, int M, int N, int K, int act)
{
    __shared__ __align__(16) bf16 As[128 * 32];
    __shared__ __align__(16) bf16 Bs[128 * 32];
    const int tid = threadIdx.x;
    const int lane = tid & 63, wid = tid >> 6;
    const int lo = lane & 15, hi = lane >> 4;
    const int m0 = blockIdx.x * 128, n0 = blockIdx.y * 128;
    const int wr = wid >> 1, wc = wid & 1;
    f32x4 acc[4][4];
#pragma unroll
    for (int i = 0; i < 4; ++i)
#pragma unroll
        for (int j = 0; j < 4; ++j) acc[i][j] = f32x4{0.f, 0.f, 0.f, 0.f};

    for (int k0 = 0; k0 < K; k0 += 32) {
        __syncthreads();
#pragma unroll
        for (int it = 0; it < 2; ++it) {
            int f = it * 256 + tid;
            int row = f >> 2, p = (f & 3) * 8;
            *(float4*)&As[row * 32 + p] = *(const float4*)&A[(size_t)(m0 + row) * K + k0 + p];
            *(float4*)&Bs[row * 32 + p] = *(const float4*)&BT[(size_t)(n0 + row) * K + k0 + p];
        }
        __syncthreads();
        bf16x8 af[4], bfr[4];
#pragma unroll
        for (int i = 0; i < 4; ++i) af[i] = *(const bf16x8*)&As[(wr * 64 + i * 16 + lo) * 32 + hi * 8];
#pragma unroll
        for (int j = 0; j < 4; ++j) bfr[j] = *(const bf16x8*)&Bs[(wc * 64 + j * 16 + lo) * 32 + hi * 8];
#pragma unroll
        for (int i = 0; i < 4; ++i)
#pragma unroll
            for (int j = 0; j < 4; ++j)
                acc[i][j] = __builtin_amdgcn_mfma_f32_16x16x32_bf16(af[i], bfr[j], acc[i][j], 0, 0, 0);
    }
#pragma unroll
    for (int i = 0; i < 4; ++i)
#pragma unroll
        for (int j = 0; j < 4; ++j) {
            int col = n0 + wc * 64 + j * 16 + lo;
            float bv = bias[col];
#pragma unroll
            for (int r = 0; r < 4; ++r) {
                int row = m0 + wr * 64 + i * 16 + hi * 4 + r;
                float v = acc[i][j][r] + bv;
                if (act == 1) v = 0.5f * v * (1.f + erff(v * 0.70710678118654752f));
                if (resid) v += (float)resid[(size_t)row * N + col];
                if (Cb) Cb[(size_t)row * N + col] = (bf16)v;
                else    Cf[(size_t)row * N + col] = v;
            }
        }
}

// ---------------------------------------------------------------------------
// V transpose: vT[b][h][d][m] = kvproj[b*1024+m][256 + h*32 + d]  (bf16)
// block: (b, h, m-chunk of 64). 1024 blocks.
// ---------------------------------------------------------------------------
__global__ __launch_bounds__(256) void vtrans_kernel(const bf16* __restrict__ kvp,
                                                     bf16* __restrict__ vT)
{
    __shared__ __align__(16) bf16 tile[64][40];
    int bid = blockIdx.x;
    int mc = bid & 15, h = (bid >> 4) & 7, b = bid >> 7;
    int t = threadIdx.x;
    {
        int m = t >> 2, p = (t & 3) * 8;
        *(float4*)&tile[m][p] =
            *(const float4*)&kvp[(size_t)(b * 1024 + mc * 64 + m) * 512 + 256 + h * 32 + p];
    }
    __syncthreads();
#pragma unroll
    for (int it = 0; it < 8; ++it) {
        int f = it * 256 + t;
        int d = f >> 6, m = f & 63;
        vT[(size_t)((b * 8 + h) * 32 + d) * 1024 + mc * 64 + m] = tile[m][d];
    }
}

// ---------------------------------------------------------------------------
// Flash attention with continuous-position bias.
// grid (32 q-tiles, 8 heads, 2 batch-groups); block = 4 waves, wave = batch.
// Per wave: 32 q-rows, loop 32 key-tiles of 32. Softmax online, fp32.
// QK^T: D[q][key] = mfma(Qfrag, Kfrag).  PV: out^T[d][q] = mfma(VTfrag, Pfrag).
// ---------------------------------------------------------------------------
__global__ __launch_bounds__(256) void attn_kernel(
    const bf16* __restrict__ qh, const bf16* __restrict__ kvp, const bf16* __restrict__ vT,
    const int* __restrict__ ridx, const float* __restrict__ cpbh,
    bf16* __restrict__ attnout, int L)
{
    __shared__ __align__(16) bf16 cpb_s[4096];
    __shared__ __align__(16) bf16 Ks[4][32 * 40];
    __shared__ __align__(16) bf16 Vs[4][32 * 40];
    __shared__ __align__(16) bf16 Ps[4][32 * 40];
    __shared__ float al_s[4][64];
    const int tid = threadIdx.x, lane = tid & 63, wid = tid >> 6;
    const int lo = lane & 15, hi = lane >> 4;
    const int n0 = blockIdx.x * 32;
    const int h = blockIdx.y;
    const int b = blockIdx.z * 4 + wid;
    const float scale = 0.17677669529663687f;  // 1/sqrt(32)

    for (int i = tid; i < L && i < 4096; i += 256) cpb_s[i] = (bf16)cpbh[(size_t)h * L + i];
    __syncthreads();

    bf16x8 qf[2];
#pragma unroll
    for (int mi = 0; mi < 2; ++mi)
        qf[mi] = *(const bf16x8*)&qh[(size_t)(b * 1024 + n0 + mi * 16 + lo) * 256 + h * 32 + hi * 8];

    f32x4 acc[2][2];
#pragma unroll
    for (int i = 0; i < 2; ++i)
#pragma unroll
        for (int j = 0; j < 2; ++j) acc[i][j] = f32x4{0.f, 0.f, 0.f, 0.f};
    float mrow[8], lrow[8];
#pragma unroll
    for (int i = 0; i < 8; ++i) { mrow[i] = -1e30f; lrow[i] = 0.f; }

    bf16* Kw = Ks[wid];
    bf16* Vw = Vs[wid];
    bf16* Pw = Ps[wid];
    volatile float* alw = al_s[wid];
    const f32x4 zero4 = {0.f, 0.f, 0.f, 0.f};

    for (int t = 0; t < 32; ++t) {
        int m0 = t * 32;
        // stage K [32 keys][32 d] (pad 40) and VT [32 d][32 m] (pad 40), per-wave
#pragma unroll
        for (int it = 0; it < 2; ++it) {
            int f = it * 64 + lane;
            int rr = f >> 2, p = (f & 3) * 8;
            *(float4*)&Kw[rr * 40 + p] =
                *(const float4*)&kvp[(size_t)(b * 1024 + m0 + rr) * 512 + h * 32 + p];
            *(float4*)&Vw[rr * 40 + p] =
                *(const float4*)&vT[(size_t)((b * 8 + h) * 32 + rr) * 1024 + m0 + p];
        }
        // QK^T
        bf16x8 kf0 = *(const bf16x8*)&Kw[lo * 40 + hi * 8];
        bf16x8 kf1 = *(const bf16x8*)&Kw[(16 + lo) * 40 + hi * 8];
        f32x4 s[2][2];
#pragma unroll
        for (int mi = 0; mi < 2; ++mi) {
            s[mi][0] = __builtin_amdgcn_mfma_f32_16x16x32_bf16(qf[mi], kf0, zero4, 0, 0, 0);
            s[mi][1] = __builtin_amdgcn_mfma_f32_16x16x32_bf16(qf[mi], kf1, zero4, 0, 0, 0);
        }
        // scale + position bias (gather)
#pragma unroll
        for (int mi = 0; mi < 2; ++mi)
#pragma unroll
            for (int kf = 0; kf < 2; ++kf)
#pragma unroll
                for (int r = 0; r < 4; ++r) {
                    int qrow = n0 + mi * 16 + hi * 4 + r;
                    int m = m0 + kf * 16 + lo;
                    float bias = (float)cpb_s[ridx[(size_t)qrow * 1024 + m]];
                    s[mi][kf][r] = s[mi][kf][r] * scale + bias;
                }
        // online softmax (row-reduce across lane&15)
#pragma unroll
        for (int mi = 0; mi < 2; ++mi)
#pragma unroll
            for (int r = 0; r < 4; ++r) {
                float mx = fmaxf(s[mi][0][r], s[mi][1][r]);
                mx = fmaxf(mx, __shfl_xor(mx, 1));
                mx = fmaxf(mx, __shfl_xor(mx, 2));
                mx = fmaxf(mx, __shfl_xor(mx, 4));
                mx = fmaxf(mx, __shfl_xor(mx, 8));
                int ri = mi * 4 + r;
                float mnew = fmaxf(mrow[ri], mx);
                float alpha = __expf(mrow[ri] - mnew);
                float p0 = __expf(s[mi][0][r] - mnew);
                float p1 = __expf(s[mi][1][r] - mnew);
                s[mi][0][r] = p0; s[mi][1][r] = p1;
                float rs = p0 + p1;
                rs += __shfl_xor(rs, 1);
                rs += __shfl_xor(rs, 2);
                rs += __shfl_xor(rs, 4);
                rs += __shfl_xor(rs, 8);
                lrow[ri] = lrow[ri] * alpha + rs;
                mrow[ri] = mnew;
                if (lo == 0) alw[mi * 16 + hi * 4 + r] = alpha;
            }
        // store P (bf16) [32 q][32 m] pad 40
#pragma unroll
        for (int mi = 0; mi < 2; ++mi)
#pragma unroll
            for (int kf = 0; kf < 2; ++kf)
#pragma unroll
                for (int r = 0; r < 4; ++r)
                    Pw[(mi * 16 + hi * 4 + r) * 40 + kf * 16 + lo] = (bf16)s[mi][kf][r];
        // rescale acc by alpha[q] (q = lane&15 within frag)
        float a0 = alw[lo], a1 = alw[16 + lo];
#pragma unroll
        for (int di = 0; di < 2; ++di)
#pragma unroll
            for (int r = 0; r < 4; ++r) { acc[di][0][r] *= a0; acc[di][1][r] *= a1; }
        // PV: out^T[d][q] += VT[d][m] * P^T[m][q]
        bf16x8 pb0 = *(const bf16x8*)&Pw[lo * 40 + hi * 8];
        bf16x8 pb1 = *(const bf16x8*)&Pw[(16 + lo) * 40 + hi * 8];
        bf16x8 va0 = *(const bf16x8*)&Vw[lo * 40 + hi * 8];
        bf16x8 va1 = *(const bf16x8*)&Vw[(16 + lo) * 40 + hi * 8];
        acc[0][0] = __builtin_amdgcn_mfma_f32_16x16x32_bf16(va0, pb0, acc[0][0], 0, 0, 0);
        acc[0][1] = __builtin_amdgcn_mfma_f32_16x16x32_bf16(va0, pb1, acc[0][1], 0, 0, 0);
        acc[1][0] = __builtin_amdgcn_mfma_f32_16x16x32_bf16(va1, pb0, acc[1][0], 0, 0, 0);
        acc[1][1] = __builtin_amdgcn_mfma_f32_16x16x32_bf16(va1, pb1, acc[1][1], 0, 0, 0);
    }
    // broadcast denominators and write
    if (lo == 0) {
#pragma unroll
        for (int i = 0; i < 8; ++i) alw[32 + (i >> 2) * 16 + hi * 4 + (i & 3)] = lrow[i];
    }
    float li0 = 1.f / alw[32 + lo];
    float li1 = 1.f / alw[48 + lo];
#pragma unroll
    for (int di = 0; di < 2; ++di)
#pragma unroll
        for (int qj = 0; qj < 2; ++qj)
#pragma unroll
            for (int r = 0; r < 4; ++r) {
                int qrow = n0 + qj * 16 + lo;
                int d = di * 16 + hi * 4 + r;
                float li = qj ? li1 : li0;
                attnout[(size_t)(b * 1024 + qrow) * 256 + h * 32 + d] = (bf16)(acc[di][qj][r] * li);
            }
}

// ---------------------------------------------------------------------------
// LayerNorm over last dim (256) + transpose to spatial [B][C][32][32]
// ---------------------------------------------------------------------------
__global__ __launch_bounds__(256) void ln_kernel(const float* __restrict__ z,
    const float* __restrict__ g, const float* __restrict__ bb, float* __restrict__ ysp)
{
    int row = blockIdx.x, c = threadIdx.x;
    float v = z[(size_t)row * 256 + c];
    __shared__ float red[8];
    float s = v;
#pragma unroll
    for (int d = 1; d < 64; d <<= 1) s += __shfl_xor(s, d);
    if ((c & 63) == 0) red[c >> 6] = s;
    __syncthreads();
    float mean = (red[0] + red[1] + red[2] + red[3]) * (1.f / 256.f);
    float dv = v - mean;
    float s2 = dv * dv;
#pragma unroll
    for (int d = 1; d < 64; d <<= 1) s2 += __shfl_xor(s2, d);
    if ((c & 63) == 0) red[4 + (c >> 6)] = s2;
    __syncthreads();
    float var = (red[4] + red[5] + red[6] + red[7]) * (1.f / 256.f);
    float o = dv * rsqrtf(var + 1e-5f) * g[c] + bb[c];
    int b = row >> 10, n = row & 1023;
    ysp[((size_t)(b * 256 + c) << 10) + n] = o;
}

// ---------------------------------------------------------------------------
// Bilinear 32x32 -> 128x128 (align_corners=False, edge clamp) + ReLU + x.
// One thread per 4 consecutive output w. out fp32 [B][C][128][128].
// ---------------------------------------------------------------------------
__global__ __launch_bounds__(256) void upsample_kernel(const float* __restrict__ x,
    const float* __restrict__ ysp, float* __restrict__ out)
{
    int idx = blockIdx.x * 256 + threadIdx.x;
    int w4 = idx & 31; int r1 = idx >> 5;
    int hh = r1 & 127; int r2 = r1 >> 7;
    int c = r2 & 255; int b = r2 >> 8;
    float chh = 0.25f * hh - 0.375f;
    float fi = floorf(chh);
    float fh = chh - fi;
    int i0 = (int)fi;
    int ia = i0 < 0 ? 0 : i0;
    int ib = (i0 + 1) > 31 ? 31 : (i0 + 1);
    const float* yr = ysp + ((size_t)(b * 256 + c) << 10);
    const float* ra = yr + ia * 32;
    const float* rb = yr + ib * 32;
    f4 xv = *(const f4*)&x[(size_t)idx * 4];
    f4 o;
#pragma unroll
    for (int k = 0; k < 4; ++k) {
        int ww = w4 * 4 + k;
        float cww = 0.25f * ww - 0.375f;
        float fj = floorf(cww);
        float fw = cww - fj;
        int j0 = (int)fj;
        int ja = j0 < 0 ? 0 : j0;
        int jb = (j0 + 1) > 31 ? 31 : (j0 + 1);
        float v = (1.f - fh) * ((1.f - fw) * ra[ja] + fw * ra[jb]) +
                  fh * ((1.f - fw) * rb[ja] + fw * rb[jb]);
        o[k] = xv[k] + fmaxf(v, 0.f);
    }
    *(f4*)&out[(size_t)idx * 4] = o;
}

// ---------------------------------------------------------------------------
extern "C" void kernel_launch(void* const* d_in, const int* in_sizes, int n_in,
                              void* d_out, int out_size, void* d_ws, size_t ws_size,
                              hipStream_t stream)
{
    (void)n_in; (void)out_size; (void)ws_size;
    const float* q    = (const float*)d_in[0];
    const float* kv   = (const float*)d_in[1];
    const int*   ridx = (const int*)d_in[2];
    const float* rtab = (const float*)d_in[3];
    const float* Wq   = (const float*)d_in[4];
    const float* bq   = (const float*)d_in[5];
    const float* Wkv  = (const float*)d_in[6];
    const float* bkv  = (const float*)d_in[7];
    const float* Wo   = (const float*)d_in[8];
    const float* bo   = (const float*)d_in[9];
    const float* cw1  = (const float*)d_in[10];
    const float* cb1  = (const float*)d_in[11];
    const float* cw2  = (const float*)d_in[12];
    const float* cb2  = (const float*)d_in[13];
    const float* fw1  = (const float*)d_in[14];
    const float* fb1  = (const float*)d_in[15];
    const float* fw2  = (const float*)d_in[16];
    const float* fb2  = (const float*)d_in[17];
    const float* lng  = (const float*)d_in[18];
    const float* lnb  = (const float*)d_in[19];
    const int L = in_sizes[3] / 2;   // rel_coords_table is [L][2]

    char* w = (char*)d_ws;
    auto alloc = [&](size_t bytes) { char* p = w; w += (bytes + 255) & ~(size_t)255; return p; };
    bf16* qt      = (bf16*)alloc(8192ull * 256 * 2);
    bf16* kvt     = (bf16*)alloc(8192ull * 256 * 2);
    bf16* qhb     = (bf16*)alloc(8192ull * 256 * 2);
    bf16* kvpb    = (bf16*)alloc(8192ull * 512 * 2);
    bf16* vTb     = (bf16*)alloc(8ull * 8 * 32 * 1024 * 2);
    bf16* attnb   = (bf16*)alloc(8192ull * 256 * 2);
    bf16* outb    = (bf16*)alloc(8192ull * 256 * 2);
    bf16* ffh     = (bf16*)alloc(8192ull * 1024 * 2);
    float* z      = (float*)alloc(8192ull * 256 * 4);
    float* ysp    = (float*)alloc(8192ull * 256 * 4);
    bf16* WqT     = (bf16*)alloc(256ull * 256 * 2);
    bf16* WkvT    = (bf16*)alloc(512ull * 256 * 2);
    bf16* WoT     = (bf16*)alloc(256ull * 256 * 2);
    bf16* W1T     = (bf16*)alloc(1024ull * 256 * 2);
    bf16* W2T     = (bf16*)alloc(256ull * 1024 * 2);
    float* cpbb   = (float*)alloc((size_t)8 * L * 4);

    wtrans_kernel<<<dim3(256),  256, 0, stream>>>(Wq,  WqT,  256, 256);
    wtrans_kernel<<<dim3(512),  256, 0, stream>>>(Wkv, WkvT, 256, 512);
    wtrans_kernel<<<dim3(256),  256, 0, stream>>>(Wo,  WoT,  256, 256);
    wtrans_kernel<<<dim3(1024), 256, 0, stream>>>(fw1, W1T,  256, 1024);
    wtrans_kernel<<<dim3(1024), 256, 0, stream>>>(fw2, W2T,  1024, 256);
    cpb_kernel<<<dim3((L + 255) / 256), 256, 0, stream>>>(rtab, cw1, cb1, cw2, cb2, cpbb, L);
    downsample_kernel<<<dim3(2048), 256, 0, stream>>>(q,  qt);
    downsample_kernel<<<dim3(2048), 256, 0, stream>>>(kv, kvt);
    // qh = qt @ Wq + bq   -> bf16 [8192][256]
    gemm_bt<<<dim3(64, 2), 256, 0, stream>>>(qt, WqT, bq, qhb, nullptr, nullptr, 8192, 256, 256, 0);
    // kvproj = kvt @ Wkv + bkv -> bf16 [8192][512]
    gemm_bt<<<dim3(64, 4), 256, 0, stream>>>(kvt, WkvT, bkv, kvpb, nullptr, nullptr, 8192, 512, 256, 0);
    vtrans_kernel<<<dim3(1024), 256, 0, stream>>>(kvpb, vTb);
    attn_kernel<<<dim3(32, 8, 2), 256, 0, stream>>>(qhb, kvpb, vTb, ridx, cpbb, attnb, L);
    // out = attn @ Wo + bo
    gemm_bt<<<dim3(64, 2), 256, 0, stream>>>(attnb, WoT, bo, outb, nullptr, nullptr, 8192, 256, 256, 0);
    // ffh = gelu(out @ ffn_w1 + b1)
    gemm_bt<<<dim3(64, 8), 256, 0, stream>>>(outb, W1T, fb1, ffh, nullptr, nullptr, 8192, 1024, 256, 1);
    // z = ffh @ ffn_w2 + b2 + out  (fp32)
    gemm_bt<<<dim3(64, 2), 256, 0, stream>>>(ffh, W2T, fb2, nullptr, z, outb, 8192, 256, 1024, 0);
    ln_kernel<<<dim3(8192), 256, 0, stream>>>(z, lng, lnb, ysp);
    upsample_kernel<<<dim3(32768), 256, 0, stream>>>(q, ysp, (float*)d_out);
}

// Round 2
// 297.181 us; speedup vs baseline: 1.6977x; 1.6977x over previous
//
#include <hip/hip_runtime.h>
#include <hip/hip_bf16.h>
#include <hip/hip_fp16.h>

typedef __hip_bfloat16 bf16;
typedef __attribute__((ext_vector_type(8))) __bf16 bf16x8;   // 8 bf16 = 4 VGPRs (MFMA A/B frag)
typedef __attribute__((ext_vector_type(4))) __bf16 bf16x4;   // 8B packed store
typedef __attribute__((ext_vector_type(4))) float f32x4;     // MFMA C/D frag
typedef __attribute__((ext_vector_type(4))) float f4;        // indexable float4

// ---------------------------------------------------------------------------
// Downsample 128x128 -> 32x32 (align_corners=False, scale 4 => avg of the
// 2x2 block at rows/cols {4i+1,4i+2}), then ReLU, write bf16 [B*1024][256].
// ---------------------------------------------------------------------------
__global__ __launch_bounds__(256) void downsample_kernel(const float* __restrict__ src,
                                                         bf16* __restrict__ dst)
{
    __shared__ float o[32][33];
    int bid = blockIdx.x;
    int cc = bid & 7, i = (bid >> 3) & 31, b = bid >> 8;
    int t = threadIdx.x;
#pragma unroll
    for (int p = 0; p < 4; ++p) {
        int id = p * 256 + t;
        int c = id >> 5, j = id & 31;
        const float* r = src + ((size_t)(b * 256 + cc * 32 + c) * 128 + 4 * i + 1) * 128 + 4 * j;
        float4 r1 = *(const float4*)r;
        float4 r2 = *(const float4*)(r + 128);
        o[c][j] = 0.25f * (r1.y + r1.z + r2.y + r2.z);
    }
    __syncthreads();
#pragma unroll
    for (int p = 0; p < 4; ++p) {
        int id = p * 256 + t;
        int j = id >> 5, c = id & 31;
        dst[(size_t)(b * 1024 + i * 32 + j) * 256 + cc * 32 + c] = (bf16)fmaxf(o[c][j], 0.f);
    }
}

// ---------------------------------------------------------------------------
// Weight transpose+cast: WT[n][k] = bf16(W[k][n])
// ---------------------------------------------------------------------------
__global__ void wtrans_kernel(const float* __restrict__ W, bf16* __restrict__ WT, int K, int N)
{
    int idx = blockIdx.x * 256 + threadIdx.x;
    if (idx >= K * N) return;
    int n = idx / K, k = idx % K;
    WT[idx] = (bf16)W[(size_t)k * N + n];
}

// ---------------------------------------------------------------------------
// CPB MLP: table[L][2] -> relu(@w1[2][512]+b1) @ w2[512][8]+b2 -> out[h][L]
// ---------------------------------------------------------------------------
__global__ __launch_bounds__(256) void cpb_kernel(const float* __restrict__ tab,
    const float* __restrict__ w1, const float* __restrict__ b1,
    const float* __restrict__ w2, const float* __restrict__ b2,
    float* __restrict__ outp, int L)
{
    int l = blockIdx.x * 256 + threadIdx.x;
    if (l >= L) return;
    float t0 = tab[2 * l], t1 = tab[2 * l + 1];
    float acc[8];
#pragma unroll
    for (int hh = 0; hh < 8; ++hh) acc[hh] = b2[hh];
    for (int j = 0; j < 512; ++j) {
        float hv = fmaxf(t0 * w1[j] + t1 * w1[512 + j] + b1[j], 0.f);
#pragma unroll
        for (int hh = 0; hh < 8; ++hh) acc[hh] += hv * w2[j * 8 + hh];
    }
#pragma unroll
    for (int hh = 0; hh < 8; ++hh) outp[(size_t)hh * L + l] = acc[hh];
}

// ---------------------------------------------------------------------------
// Fragment-ordered bias gather: biasF[h][qt][mt][qj][lane][8] (bf16), where
// slot j = kf*4+r holds cpb[h][ridx[q*1024+m]] for
// q = qt*32+qj*16+(lane&15), m = mt*32+kf*16+(lane>>4)*4+r.
// This matches the C/D layout of s[kf][qj] = mfma(Kfrag, Qfrag).
// 65536 threads (256 blocks).
// ---------------------------------------------------------------------------
__global__ __launch_bounds__(256) void bias_gather_kernel(
    const int* __restrict__ ridx, const float* __restrict__ cpbh,
    bf16* __restrict__ biasF, int L)
{
    int gid = blockIdx.x * 256 + threadIdx.x;
    int ls = gid & 63;
    int mt = (gid >> 6) & 31;
    int qt = gid >> 11;
    int lo = ls & 15, hi = ls >> 4;
    int idx[2][8];
#pragma unroll
    for (int qj = 0; qj < 2; ++qj)
#pragma unroll
        for (int j = 0; j < 8; ++j) {
            int kf = j >> 2, r = j & 3;
            int q = qt * 32 + qj * 16 + lo;
            int m = mt * 32 + kf * 16 + hi * 4 + r;
            idx[qj][j] = ridx[q * 1024 + m];
        }
    for (int h = 0; h < 8; ++h) {
        const float* ct = cpbh + (size_t)h * L;
#pragma unroll
        for (int qj = 0; qj < 2; ++qj) {
            bf16 vals[8];
#pragma unroll
            for (int j = 0; j < 8; ++j) vals[j] = (bf16)ct[idx[qj][j]];
            size_t off = ((((size_t)(h * 32 + qt) * 32 + mt) * 2 + qj) * 64 + ls) * 8;
            *(bf16x8*)&biasF[off] = *(const bf16x8*)vals;
        }
    }
}

// ---------------------------------------------------------------------------
// Generic bf16 MFMA GEMM: C[M][N] = act(A[M][K] @ BT[N][K]^T + bias) (+resid)
// 128xBN tile, BK=32, 4 waves (2x2), wave tile 64 x BN/2.
// ---------------------------------------------------------------------------
template<int BN>
__global__ __launch_bounds__(256) void gemm_bt(
    const bf16* __restrict__ A, const bf16* __restrict__ BT,
    const float* __restrict__ bias, bf16* __restrict__ Cb, float* __restrict__ Cf,
    const bf16* __restrict__ resid, int M, int N, int K, int act)
{
    constexpr int NJ = BN / 32;   // col frags per wave
    __shared__ __align__(16) bf16 As[128 * 32];
    __shared__ __align__(16) bf16 Bs[BN * 32];
    const int tid = threadIdx.x;
    const int lane = tid & 63, wid = tid >> 6;
    const int lo = lane & 15, hi = lane >> 4;
    const int m0 = blockIdx.x * 128, n0 = blockIdx.y * BN;
    const int wr = wid >> 1, wc = wid & 1;
    f32x4 acc[4][NJ];
#pragma unroll
    for (int i = 0; i < 4; ++i)
#pragma unroll
        for (int j = 0; j < NJ; ++j) acc[i][j] = f32x4{0.f, 0.f, 0.f, 0.f};

    for (int k0 = 0; k0 < K; k0 += 32) {
        __syncthreads();
#pragma unroll
        for (int it = 0; it < 2; ++it) {
            int f = it * 256 + tid;
            int row = f >> 2, p = (f & 3) * 8;
            *(float4*)&As[row * 32 + p] = *(const float4*)&A[(size_t)(m0 + row) * K + k0 + p];
        }
#pragma unroll
        for (int it = 0; it < BN / 64; ++it) {
            int f = it * 256 + tid;
            int row = f >> 2, p = (f & 3) * 8;
            *(float4*)&Bs[row * 32 + p] = *(const float4*)&BT[(size_t)(n0 + row) * K + k0 + p];
        }
        __syncthreads();
        bf16x8 af[4], bfr[NJ];
#pragma unroll
        for (int i = 0; i < 4; ++i) af[i] = *(const bf16x8*)&As[(wr * 64 + i * 16 + lo) * 32 + hi * 8];
#pragma unroll
        for (int j = 0; j < NJ; ++j) bfr[j] = *(const bf16x8*)&Bs[(wc * (BN / 2) + j * 16 + lo) * 32 + hi * 8];
#pragma unroll
        for (int i = 0; i < 4; ++i)
#pragma unroll
            for (int j = 0; j < NJ; ++j)
                acc[i][j] = __builtin_amdgcn_mfma_f32_16x16x32_bf16(af[i], bfr[j], acc[i][j], 0, 0, 0);
    }
#pragma unroll
    for (int i = 0; i < 4; ++i)
#pragma unroll
        for (int j = 0; j < NJ; ++j) {
            int col = n0 + wc * (BN / 2) + j * 16 + lo;
            float bv = bias[col];
#pragma unroll
            for (int r = 0; r < 4; ++r) {
                int row = m0 + wr * 64 + i * 16 + hi * 4 + r;
                float v = acc[i][j][r] + bv;
                if (act == 1) v = 0.5f * v * (1.f + erff(v * 0.70710678118654752f));
                if (resid) v += (float)resid[(size_t)row * N + col];
                if (Cb) Cb[(size_t)row * N + col] = (bf16)v;
                else    Cf[(size_t)row * N + col] = v;
            }
        }
}

// ---------------------------------------------------------------------------
// V transpose: vT[b][h][d][m] = kvproj[b*1024+m][256 + h*32 + d]  (bf16)
// ---------------------------------------------------------------------------
__global__ __launch_bounds__(256) void vtrans_kernel(const bf16* __restrict__ kvp,
                                                     bf16* __restrict__ vT)
{
    __shared__ __align__(16) bf16 tile[64][40];
    int bid = blockIdx.x;
    int mc = bid & 15, h = (bid >> 4) & 7, b = bid >> 7;
    int t = threadIdx.x;
    {
        int m = t >> 2, p = (t & 3) * 8;
        *(float4*)&tile[m][p] =
            *(const float4*)&kvp[(size_t)(b * 1024 + mc * 64 + m) * 512 + 256 + h * 32 + p];
    }
    __syncthreads();
#pragma unroll
    for (int it = 0; it < 8; ++it) {
        int f = it * 256 + t;
        int d = f >> 6, m = f & 63;
        vT[(size_t)((b * 8 + h) * 32 + d) * 1024 + mc * 64 + m] = tile[m][d];
    }
}

// ---------------------------------------------------------------------------
// Flash attention v3: swapped-QK orientation, key-split across 4 waves.
// grid (32 q-tiles, 8 heads, 8 batches); block = 4 waves.
// Wave w handles key tiles {w, w+4, ..., w+28}; partials merged via LDS.
// QK^T: s[kf][qj] = mfma(Kfrag, Qfrag) -> lane holds q=lane&15 (lane-local
// softmax, no LDS broadcasts). PV: acc[di][qj] = mfma(VTfrag, Pfrag).
// ---------------------------------------------------------------------------
__global__ __launch_bounds__(256) void attn_kernel(
    const bf16* __restrict__ qh, const bf16* __restrict__ kvp, const bf16* __restrict__ vT,
    const bf16* __restrict__ biasF, bf16* __restrict__ attnout)
{
    __shared__ __align__(16) bf16 Ps[4][32 * 40];
    __shared__ __align__(16) __half accs[4][32][34];   // [w][d][q]
    __shared__ float pm[4][32], pl[4][32];
    const int tid = threadIdx.x, lane = tid & 63, wid = tid >> 6;
    const int lo = lane & 15, hi = lane >> 4;
    const int qt = blockIdx.x, n0 = qt * 32;
    const int h = blockIdx.y;
    const int b = blockIdx.z;
    const float scale = 0.17677669529663687f;  // 1/sqrt(32)
    const f32x4 zero4 = {0.f, 0.f, 0.f, 0.f};

    // Q fragments (B operand): q = qj*16+lo, k(d) = hi*8..+7
    bf16x8 qf[2];
#pragma unroll
    for (int qj = 0; qj < 2; ++qj)
        qf[qj] = *(const bf16x8*)&qh[(size_t)(b * 1024 + n0 + qj * 16 + lo) * 256 + h * 32 + hi * 8];

    f32x4 acc[2][2];  // [di][qj]: out^T[d][q]
#pragma unroll
    for (int i = 0; i < 2; ++i)
#pragma unroll
        for (int j = 0; j < 2; ++j) acc[i][j] = zero4;
    float mrow[2] = {-1e30f, -1e30f}, lrow[2] = {0.f, 0.f};

    bf16* Pw = Ps[wid];

    for (int t = wid; t < 32; t += 4) {
        const int m0 = t * 32;
        // K fragments (A operand): m = kf*16+lo, k(d) = hi*8..+7
        bf16x8 kfr0 = *(const bf16x8*)&kvp[(size_t)(b * 1024 + m0 + lo) * 512 + h * 32 + hi * 8];
        bf16x8 kfr1 = *(const bf16x8*)&kvp[(size_t)(b * 1024 + m0 + 16 + lo) * 512 + h * 32 + hi * 8];
        // V^T fragments (A operand for PV): d = di*16+lo, k(m) = hi*8..+7
        bf16x8 va0 = *(const bf16x8*)&vT[(size_t)((b * 8 + h) * 32 + lo) * 1024 + m0 + hi * 8];
        bf16x8 va1 = *(const bf16x8*)&vT[(size_t)((b * 8 + h) * 32 + 16 + lo) * 1024 + m0 + hi * 8];
        // fragment-ordered bias
        size_t boff = (((size_t)(h * 32 + qt) * 32 + t) * 2 * 64 + lane) * 8;
        bf16x8 bv0 = *(const bf16x8*)&biasF[boff];
        bf16x8 bv1 = *(const bf16x8*)&biasF[boff + 512];

        f32x4 s[2][2];  // [kf][qj]: lane holds m = kf*16+hi*4+r, q = qj*16+lo
        s[0][0] = __builtin_amdgcn_mfma_f32_16x16x32_bf16(kfr0, qf[0], zero4, 0, 0, 0);
        s[0][1] = __builtin_amdgcn_mfma_f32_16x16x32_bf16(kfr0, qf[1], zero4, 0, 0, 0);
        s[1][0] = __builtin_amdgcn_mfma_f32_16x16x32_bf16(kfr1, qf[0], zero4, 0, 0, 0);
        s[1][1] = __builtin_amdgcn_mfma_f32_16x16x32_bf16(kfr1, qf[1], zero4, 0, 0, 0);
#pragma unroll
        for (int kf = 0; kf < 2; ++kf)
#pragma unroll
            for (int r = 0; r < 4; ++r) {
                s[kf][0][r] = s[kf][0][r] * scale + (float)bv0[kf * 4 + r];
                s[kf][1][r] = s[kf][1][r] * scale + (float)bv1[kf * 4 + r];
            }
        // online softmax, per lane-local q
#pragma unroll
        for (int qj = 0; qj < 2; ++qj) {
            float mx = fmaxf(fmaxf(fmaxf(s[0][qj][0], s[0][qj][1]), fmaxf(s[0][qj][2], s[0][qj][3])),
                             fmaxf(fmaxf(s[1][qj][0], s[1][qj][1]), fmaxf(s[1][qj][2], s[1][qj][3])));
            mx = fmaxf(mx, __shfl_xor(mx, 16));
            mx = fmaxf(mx, __shfl_xor(mx, 32));
            float mnew = fmaxf(mrow[qj], mx);
            float alpha = __expf(mrow[qj] - mnew);
            float rs = 0.f;
#pragma unroll
            for (int kf = 0; kf < 2; ++kf)
#pragma unroll
                for (int r = 0; r < 4; ++r) {
                    float p = __expf(s[kf][qj][r] - mnew);
                    s[kf][qj][r] = p;
                    rs += p;
                }
            rs += __shfl_xor(rs, 16);
            rs += __shfl_xor(rs, 32);
            lrow[qj] = lrow[qj] * alpha + rs;
            mrow[qj] = mnew;
#pragma unroll
            for (int di = 0; di < 2; ++di)
#pragma unroll
                for (int r = 0; r < 4; ++r) acc[di][qj][r] *= alpha;
        }
        // P -> LDS as [q][m] (pad 40), then read as B-frag
#pragma unroll
        for (int qj = 0; qj < 2; ++qj)
#pragma unroll
            for (int kf = 0; kf < 2; ++kf)
#pragma unroll
                for (int r = 0; r < 4; ++r)
                    Pw[(qj * 16 + lo) * 40 + kf * 16 + hi * 4 + r] = (bf16)s[kf][qj][r];
        bf16x8 pb0 = *(const bf16x8*)&Pw[lo * 40 + hi * 8];
        bf16x8 pb1 = *(const bf16x8*)&Pw[(16 + lo) * 40 + hi * 8];
        acc[0][0] = __builtin_amdgcn_mfma_f32_16x16x32_bf16(va0, pb0, acc[0][0], 0, 0, 0);
        acc[0][1] = __builtin_amdgcn_mfma_f32_16x16x32_bf16(va0, pb1, acc[0][1], 0, 0, 0);
        acc[1][0] = __builtin_amdgcn_mfma_f32_16x16x32_bf16(va1, pb0, acc[1][0], 0, 0, 0);
        acc[1][1] = __builtin_amdgcn_mfma_f32_16x16x32_bf16(va1, pb1, acc[1][1], 0, 0, 0);
    }
    // write partials
#pragma unroll
    for (int di = 0; di < 2; ++di)
#pragma unroll
        for (int qj = 0; qj < 2; ++qj)
#pragma unroll
            for (int r = 0; r < 4; ++r)
                accs[wid][di * 16 + hi * 4 + r][qj * 16 + lo] = __float2half(acc[di][qj][r]);
    if (hi == 0) {
#pragma unroll
        for (int qj = 0; qj < 2; ++qj) {
            pm[wid][qj * 16 + lo] = mrow[qj];
            pl[wid][qj * 16 + lo] = lrow[qj];
        }
    }
    __syncthreads();
    // merge 4 partials: thread -> q = tid>>3, d = (tid&7)*4 + j
    int q = tid >> 3, d0 = (tid & 7) * 4;
    float M = fmaxf(fmaxf(pm[0][q], pm[1][q]), fmaxf(pm[2][q], pm[3][q]));
    float f0 = __expf(pm[0][q] - M), f1 = __expf(pm[1][q] - M);
    float f2 = __expf(pm[2][q] - M), f3 = __expf(pm[3][q] - M);
    float inv = 1.f / (pl[0][q] * f0 + pl[1][q] * f1 + pl[2][q] * f2 + pl[3][q] * f3);
    bf16 tmp[4];
#pragma unroll
    for (int j = 0; j < 4; ++j) {
        int d = d0 + j;
        float o = f0 * (float)accs[0][d][q] + f1 * (float)accs[1][d][q] +
                  f2 * (float)accs[2][d][q] + f3 * (float)accs[3][d][q];
        tmp[j] = (bf16)(o * inv);
    }
    *(bf16x4*)&attnout[(size_t)(b * 1024 + n0 + q) * 256 + h * 32 + d0] = *(const bf16x4*)tmp;
}

// ---------------------------------------------------------------------------
// LayerNorm over last dim (256) + transpose to spatial [B][C][32][32]
// ---------------------------------------------------------------------------
__global__ __launch_bounds__(256) void ln_kernel(const float* __restrict__ z,
    const float* __restrict__ g, const float* __restrict__ bb, float* __restrict__ ysp)
{
    int row = blockIdx.x, c = threadIdx.x;
    float v = z[(size_t)row * 256 + c];
    __shared__ float red[8];
    float s = v;
#pragma unroll
    for (int d = 1; d < 64; d <<= 1) s += __shfl_xor(s, d);
    if ((c & 63) == 0) red[c >> 6] = s;
    __syncthreads();
    float mean = (red[0] + red[1] + red[2] + red[3]) * (1.f / 256.f);
    float dv = v - mean;
    float s2 = dv * dv;
#pragma unroll
    for (int d = 1; d < 64; d <<= 1) s2 += __shfl_xor(s2, d);
    if ((c & 63) == 0) red[4 + (c >> 6)] = s2;
    __syncthreads();
    float var = (red[4] + red[5] + red[6] + red[7]) * (1.f / 256.f);
    float o = dv * rsqrtf(var + 1e-5f) * g[c] + bb[c];
    int b = row >> 10, n = row & 1023;
    ysp[((size_t)(b * 256 + c) << 10) + n] = o;
}

// ---------------------------------------------------------------------------
// Bilinear 32x32 -> 128x128 (align_corners=False, edge clamp) + ReLU + x.
// ---------------------------------------------------------------------------
__global__ __launch_bounds__(256) void upsample_kernel(const float* __restrict__ x,
    const float* __restrict__ ysp, float* __restrict__ out)
{
    int idx = blockIdx.x * 256 + threadIdx.x;
    int w4 = idx & 31; int r1 = idx >> 5;
    int hh = r1 & 127; int r2 = r1 >> 7;
    int c = r2 & 255; int b = r2 >> 8;
    float chh = 0.25f * hh - 0.375f;
    float fi = floorf(chh);
    float fh = chh - fi;
    int i0 = (int)fi;
    int ia = i0 < 0 ? 0 : i0;
    int ib = (i0 + 1) > 31 ? 31 : (i0 + 1);
    const float* yr = ysp + ((size_t)(b * 256 + c) << 10);
    const float* ra = yr + ia * 32;
    const float* rb = yr + ib * 32;
    f4 xv = *(const f4*)&x[(size_t)idx * 4];
    f4 o;
#pragma unroll
    for (int k = 0; k < 4; ++k) {
        int ww = w4 * 4 + k;
        float cww = 0.25f * ww - 0.375f;
        float fj = floorf(cww);
        float fw = cww - fj;
        int j0 = (int)fj;
        int ja = j0 < 0 ? 0 : j0;
        int jb = (j0 + 1) > 31 ? 31 : (j0 + 1);
        float v = (1.f - fh) * ((1.f - fw) * ra[ja] + fw * ra[jb]) +
                  fh * ((1.f - fw) * rb[ja] + fw * rb[jb]);
        o[k] = xv[k] + fmaxf(v, 0.f);
    }
    *(f4*)&out[(size_t)idx * 4] = o;
}

// ---------------------------------------------------------------------------
extern "C" void kernel_launch(void* const* d_in, const int* in_sizes, int n_in,
                              void* d_out, int out_size, void* d_ws, size_t ws_size,
                              hipStream_t stream)
{
    (void)n_in; (void)out_size; (void)ws_size;
    const float* q    = (const float*)d_in[0];
    const float* kv   = (const float*)d_in[1];
    const int*   ridx = (const int*)d_in[2];
    const float* rtab = (const float*)d_in[3];
    const float* Wq   = (const float*)d_in[4];
    const float* bq   = (const float*)d_in[5];
    const float* Wkv  = (const float*)d_in[6];
    const float* bkv  = (const float*)d_in[7];
    const float* Wo   = (const float*)d_in[8];
    const float* bo   = (const float*)d_in[9];
    const float* cw1  = (const float*)d_in[10];
    const float* cb1  = (const float*)d_in[11];
    const float* cw2  = (const float*)d_in[12];
    const float* cb2  = (const float*)d_in[13];
    const float* fw1  = (const float*)d_in[14];
    const float* fb1  = (const float*)d_in[15];
    const float* fw2  = (const float*)d_in[16];
    const float* fb2  = (const float*)d_in[17];
    const float* lng  = (const float*)d_in[18];
    const float* lnb  = (const float*)d_in[19];
    const int L = in_sizes[3] / 2;   // rel_coords_table is [L][2]

    char* w = (char*)d_ws;
    auto alloc = [&](size_t bytes) { char* p = w; w += (bytes + 255) & ~(size_t)255; return p; };
    bf16* qt      = (bf16*)alloc(8192ull * 256 * 2);
    bf16* kvt     = (bf16*)alloc(8192ull * 256 * 2);
    bf16* qhb     = (bf16*)alloc(8192ull * 256 * 2);
    bf16* kvpb    = (bf16*)alloc(8192ull * 512 * 2);
    bf16* vTb     = (bf16*)alloc(8ull * 8 * 32 * 1024 * 2);
    bf16* attnb   = (bf16*)alloc(8192ull * 256 * 2);
    bf16* outb    = (bf16*)alloc(8192ull * 256 * 2);
    bf16* ffh     = (bf16*)alloc(8192ull * 1024 * 2);   // aliased: biasF before FFN1
    float* z      = (float*)alloc(8192ull * 256 * 4);
    float* ysp    = (float*)alloc(8192ull * 256 * 4);
    bf16* WqT     = (bf16*)alloc(256ull * 256 * 2);
    bf16* WkvT    = (bf16*)alloc(512ull * 256 * 2);
    bf16* WoT     = (bf16*)alloc(256ull * 256 * 2);
    bf16* W1T     = (bf16*)alloc(1024ull * 256 * 2);
    bf16* W2T     = (bf16*)alloc(256ull * 1024 * 2);
    float* cpbb   = (float*)alloc((size_t)8 * L * 4);
    bf16* biasF   = ffh;   // 16.78 MB, dead before ffh is first written

    wtrans_kernel<<<dim3(256),  256, 0, stream>>>(Wq,  WqT,  256, 256);
    wtrans_kernel<<<dim3(512),  256, 0, stream>>>(Wkv, WkvT, 256, 512);
    wtrans_kernel<<<dim3(256),  256, 0, stream>>>(Wo,  WoT,  256, 256);
    wtrans_kernel<<<dim3(1024), 256, 0, stream>>>(fw1, W1T,  256, 1024);
    wtrans_kernel<<<dim3(1024), 256, 0, stream>>>(fw2, W2T,  1024, 256);
    cpb_kernel<<<dim3((L + 255) / 256), 256, 0, stream>>>(rtab, cw1, cb1, cw2, cb2, cpbb, L);
    bias_gather_kernel<<<dim3(256), 256, 0, stream>>>(ridx, cpbb, biasF, L);
    downsample_kernel<<<dim3(2048), 256, 0, stream>>>(q,  qt);
    downsample_kernel<<<dim3(2048), 256, 0, stream>>>(kv, kvt);
    // qh = qt @ Wq + bq   -> bf16 [8192][256]
    gemm_bt<64><<<dim3(64, 4), 256, 0, stream>>>(qt, WqT, bq, qhb, nullptr, nullptr, 8192, 256, 256, 0);
    // kvproj = kvt @ Wkv + bkv -> bf16 [8192][512]
    gemm_bt<64><<<dim3(64, 8), 256, 0, stream>>>(kvt, WkvT, bkv, kvpb, nullptr, nullptr, 8192, 512, 256, 0);
    vtrans_kernel<<<dim3(1024), 256, 0, stream>>>(kvpb, vTb);
    attn_kernel<<<dim3(32, 8, 8), 256, 0, stream>>>(qhb, kvpb, vTb, biasF, attnb);
    // out = attn @ Wo + bo
    gemm_bt<64><<<dim3(64, 4), 256, 0, stream>>>(attnb, WoT, bo, outb, nullptr, nullptr, 8192, 256, 256, 0);
    // ffh = gelu(out @ ffn_w1 + b1)   (overwrites biasF — attn is done)
    gemm_bt<64><<<dim3(64, 16), 256, 0, stream>>>(outb, W1T, fb1, ffh, nullptr, nullptr, 8192, 1024, 256, 1);
    // z = ffh @ ffn_w2 + b2 + out  (fp32)
    gemm_bt<64><<<dim3(64, 4), 256, 0, stream>>>(ffh, W2T, fb2, nullptr, z, outb, 8192, 256, 1024, 0);
    ln_kernel<<<dim3(8192), 256, 0, stream>>>(z, lng, lnb, ysp);
    upsample_kernel<<<dim3(32768), 256, 0, stream>>>(q, ysp, (float*)d_out);
}

// Round 3
// 221.143 us; speedup vs baseline: 2.2815x; 1.3438x over previous
//
#include <hip/hip_runtime.h>
#include <hip/hip_bf16.h>
#include <hip/hip_fp16.h>

typedef __hip_bfloat16 bf16;
typedef __attribute__((ext_vector_type(8))) __bf16 bf16x8;   // 8 bf16 = 4 VGPRs (MFMA A/B frag)
typedef __attribute__((ext_vector_type(4))) __bf16 bf16x4;   // 8B packed store
typedef __attribute__((ext_vector_type(4))) float f32x4;     // MFMA C/D frag
typedef __attribute__((ext_vector_type(4))) float f4;        // indexable float4

// async global->LDS, 16B per lane. LDS dest must be wave-uniform base (lane*16 auto).
__device__ __forceinline__ void gload_lds16(const bf16* g, bf16* l)
{
    __builtin_amdgcn_global_load_lds((const __attribute__((address_space(1))) void*)g,
                                     (__attribute__((address_space(3))) void*)l, 16, 0, 0);
}

// ---------------------------------------------------------------------------
// Downsample 128x128 -> 32x32 (align_corners=False, scale 4 => avg of the
// 2x2 block at rows/cols {4i+1,4i+2}), then ReLU, write bf16 [B*1024][256].
// Fused: blocks [0,2048) do q->qt, [2048,4096) kv->kvt.
// ---------------------------------------------------------------------------
__global__ __launch_bounds__(256) void downsample_kernel(const float* __restrict__ qsrc,
                                                         const float* __restrict__ kvsrc,
                                                         bf16* __restrict__ qdst,
                                                         bf16* __restrict__ kvdst)
{
    __shared__ float o[32][33];
    const float* src = blockIdx.x < 2048 ? qsrc : kvsrc;
    bf16* dst = blockIdx.x < 2048 ? qdst : kvdst;
    int bid = blockIdx.x & 2047;
    int cc = bid & 7, i = (bid >> 3) & 31, b = bid >> 8;
    int t = threadIdx.x;
#pragma unroll
    for (int p = 0; p < 4; ++p) {
        int id = p * 256 + t;
        int c = id >> 5, j = id & 31;
        const float* r = src + ((size_t)(b * 256 + cc * 32 + c) * 128 + 4 * i + 1) * 128 + 4 * j;
        float4 r1 = *(const float4*)r;
        float4 r2 = *(const float4*)(r + 128);
        o[c][j] = 0.25f * (r1.y + r1.z + r2.y + r2.z);
    }
    __syncthreads();
#pragma unroll
    for (int p = 0; p < 4; ++p) {
        int id = p * 256 + t;
        int j = id >> 5, c = id & 31;
        dst[(size_t)(b * 1024 + i * 32 + j) * 256 + cc * 32 + c] = (bf16)fmaxf(o[c][j], 0.f);
    }
}

// ---------------------------------------------------------------------------
// All five weight transposes in one launch: WT[n][k] = bf16(W[k][n])
// ---------------------------------------------------------------------------
__global__ __launch_bounds__(256) void wtrans_all(
    const float* __restrict__ Wq, const float* __restrict__ Wkv, const float* __restrict__ Wo,
    const float* __restrict__ fw1, const float* __restrict__ fw2,
    bf16* __restrict__ WqT, bf16* __restrict__ WkvT, bf16* __restrict__ WoT,
    bf16* __restrict__ W1T, bf16* __restrict__ W2T)
{
    int bid = blockIdx.x;
    const float* W; bf16* WT; int K, N, base;
    if (bid < 256)       { W = Wq;  WT = WqT;  K = 256;  N = 256;  base = 0; }
    else if (bid < 768)  { W = Wkv; WT = WkvT; K = 256;  N = 512;  base = 256; }
    else if (bid < 1024) { W = Wo;  WT = WoT;  K = 256;  N = 256;  base = 768; }
    else if (bid < 2048) { W = fw1; WT = W1T;  K = 256;  N = 1024; base = 1024; }
    else                 { W = fw2; WT = W2T;  K = 1024; N = 256;  base = 2048; }
    int idx = (bid - base) * 256 + threadIdx.x;
    int n = idx / K, k = idx % K;
    WT[idx] = (bf16)W[(size_t)k * N + n];
}

// ---------------------------------------------------------------------------
// CPB MLP: table[L][2] -> relu(@w1[2][512]+b1) @ w2[512][8]+b2 -> out[h][L]
// 8 threads per l (j-split), shuffle-reduced. grid = ceil(L/32).
// ---------------------------------------------------------------------------
__global__ __launch_bounds__(256) void cpb_kernel(const float* __restrict__ tab,
    const float* __restrict__ w1, const float* __restrict__ b1,
    const float* __restrict__ w2, const float* __restrict__ b2,
    float* __restrict__ outp, int L)
{
    int tid = threadIdx.x;
    int l = blockIdx.x * 32 + (tid >> 3);
    int js = tid & 7;
    bool valid = l < L;
    float t0 = valid ? tab[2 * l] : 0.f, t1 = valid ? tab[2 * l + 1] : 0.f;
    float acc[8];
#pragma unroll
    for (int hh = 0; hh < 8; ++hh) acc[hh] = 0.f;
    for (int j = js; j < 512; j += 8) {
        float hv = fmaxf(t0 * w1[j] + t1 * w1[512 + j] + b1[j], 0.f);
        f4 w2a = *(const f4*)&w2[j * 8];
        f4 w2b = *(const f4*)&w2[j * 8 + 4];
#pragma unroll
        for (int hh = 0; hh < 4; ++hh) { acc[hh] += hv * w2a[hh]; acc[4 + hh] += hv * w2b[hh]; }
    }
#pragma unroll
    for (int d = 1; d < 8; d <<= 1)
#pragma unroll
        for (int hh = 0; hh < 8; ++hh) acc[hh] += __shfl_xor(acc[hh], d);
    if (js == 0 && valid)
#pragma unroll
        for (int hh = 0; hh < 8; ++hh) outp[(size_t)hh * L + l] = acc[hh] + b2[hh];
}

// ---------------------------------------------------------------------------
// Fragment-ordered bias gather: biasF[h][qt][mt][qj][lane][8] (bf16), matching
// the C/D layout of s[kf][qj] = mfma(Kfrag, Qfrag).
// ---------------------------------------------------------------------------
__global__ __launch_bounds__(256) void bias_gather_kernel(
    const int* __restrict__ ridx, const float* __restrict__ cpbh,
    bf16* __restrict__ biasF, int L)
{
    int gid = blockIdx.x * 256 + threadIdx.x;
    int ls = gid & 63;
    int mt = (gid >> 6) & 31;
    int qt = gid >> 11;
    int lo = ls & 15, hi = ls >> 4;
    int idx[2][8];
#pragma unroll
    for (int qj = 0; qj < 2; ++qj)
#pragma unroll
        for (int j = 0; j < 8; ++j) {
            int kf = j >> 2, r = j & 3;
            int q = qt * 32 + qj * 16 + lo;
            int m = mt * 32 + kf * 16 + hi * 4 + r;
            idx[qj][j] = ridx[q * 1024 + m];
        }
    for (int h = 0; h < 8; ++h) {
        const float* ct = cpbh + (size_t)h * L;
#pragma unroll
        for (int qj = 0; qj < 2; ++qj) {
            bf16 vals[8];
#pragma unroll
            for (int j = 0; j < 8; ++j) vals[j] = (bf16)ct[idx[qj][j]];
            size_t off = ((((size_t)(h * 32 + qt) * 32 + mt) * 2 + qj) * 64 + ls) * 8;
            *(bf16x8*)&biasF[off] = *(const bf16x8*)vals;
        }
    }
}

// ---------------------------------------------------------------------------
// GEMM v4: C[M][N] = act(A[M][K] @ BT[N][K]^T + bias) (+resid)
// Tile BM x BN, BK=64, 4 waves (2x2), wave tile (BM/2 x BN/2).
// Staging via async global_load_lds (linear LDS dest, XOR-swizzled global
// source: chunk cs holds data chunk cs^(row&7)) -> <=2-way LDS conflicts.
// ---------------------------------------------------------------------------
template<int BM, int BN>
__global__ __launch_bounds__(256) void gemm_bt(
    const bf16* __restrict__ A, const bf16* __restrict__ BT,
    const float* __restrict__ bias, bf16* __restrict__ Cb, float* __restrict__ Cf,
    const bf16* __restrict__ resid, int M, int N, int K, int act)
{
    constexpr int MI = BM / 32;   // row frags per wave
    constexpr int NJ = BN / 32;   // col frags per wave
    __shared__ __align__(16) bf16 As[BM * 64];
    __shared__ __align__(16) bf16 Bs[BN * 64];
    const int tid = threadIdx.x;
    const int lane = tid & 63, wid = tid >> 6;
    const int lo = lane & 15, hi = lane >> 4;
    const int m0 = blockIdx.x * BM, n0 = blockIdx.y * BN;
    const int wr = wid >> 1, wc = wid & 1;
    f32x4 acc[MI][NJ];
#pragma unroll
    for (int i = 0; i < MI; ++i)
#pragma unroll
        for (int j = 0; j < NJ; ++j) acc[i][j] = f32x4{0.f, 0.f, 0.f, 0.f};

    for (int k0 = 0; k0 < K; k0 += 64) {
        __syncthreads();
        // stage A: BM rows x 8 chunks of 16B
#pragma unroll
        for (int p = 0; p < BM / 32; ++p) {
            int f = p * 256 + wid * 64 + lane;
            int row = f >> 3, cs = f & 7;
            gload_lds16(&A[(size_t)(m0 + row) * K + k0 + ((cs ^ (row & 7)) * 8)],
                        As + (size_t)(p * 256 + wid * 64) * 8);
        }
        // stage B: BN rows x 8 chunks
#pragma unroll
        for (int p = 0; p < BN / 32; ++p) {
            int f = p * 256 + wid * 64 + lane;
            int row = f >> 3, cs = f & 7;
            gload_lds16(&BT[(size_t)(n0 + row) * K + k0 + ((cs ^ (row & 7)) * 8)],
                        Bs + (size_t)(p * 256 + wid * 64) * 8);
        }
        __syncthreads();   // drains vmcnt(0) for global_load_lds
        bf16x8 af[2][MI], bfr[2][NJ];
#pragma unroll
        for (int kk = 0; kk < 2; ++kk) {
#pragma unroll
            for (int i = 0; i < MI; ++i) {
                int row = wr * (BM / 2) + i * 16 + lo;
                af[kk][i] = *(const bf16x8*)&As[row * 64 + (((kk * 4 + hi) ^ (lo & 7)) * 8)];
            }
#pragma unroll
            for (int j = 0; j < NJ; ++j) {
                int row = wc * (BN / 2) + j * 16 + lo;
                bfr[kk][j] = *(const bf16x8*)&Bs[row * 64 + (((kk * 4 + hi) ^ (lo & 7)) * 8)];
            }
        }
#pragma unroll
        for (int kk = 0; kk < 2; ++kk)
#pragma unroll
            for (int i = 0; i < MI; ++i)
#pragma unroll
                for (int j = 0; j < NJ; ++j)
                    acc[i][j] = __builtin_amdgcn_mfma_f32_16x16x32_bf16(af[kk][i], bfr[kk][j], acc[i][j], 0, 0, 0);
    }
#pragma unroll
    for (int i = 0; i < MI; ++i)
#pragma unroll
        for (int j = 0; j < NJ; ++j) {
            int col = n0 + wc * (BN / 2) + j * 16 + lo;
            float bv = bias[col];
#pragma unroll
            for (int r = 0; r < 4; ++r) {
                int row = m0 + wr * (BM / 2) + i * 16 + hi * 4 + r;
                float v = acc[i][j][r] + bv;
                if (act == 1) v = 0.5f * v * (1.f + erff(v * 0.70710678118654752f));
                if (resid) v += (float)resid[(size_t)row * N + col];
                if (Cb) Cb[(size_t)row * N + col] = (bf16)v;
                else    Cf[(size_t)row * N + col] = v;
            }
        }
}

// ---------------------------------------------------------------------------
// V transpose: vT[b][h][d][m] = kvproj[b*1024+m][256 + h*32 + d]  (bf16)
// ---------------------------------------------------------------------------
__global__ __launch_bounds__(256) void vtrans_kernel(const bf16* __restrict__ kvp,
                                                     bf16* __restrict__ vT)
{
    __shared__ __align__(16) bf16 tile[64][40];
    int bid = blockIdx.x;
    int mc = bid & 15, h = (bid >> 4) & 7, b = bid >> 7;
    int t = threadIdx.x;
    {
        int m = t >> 2, p = (t & 3) * 8;
        *(float4*)&tile[m][p] =
            *(const float4*)&kvp[(size_t)(b * 1024 + mc * 64 + m) * 512 + 256 + h * 32 + p];
    }
    __syncthreads();
#pragma unroll
    for (int it = 0; it < 8; ++it) {
        int f = it * 256 + t;
        int d = f >> 6, m = f & 63;
        vT[(size_t)((b * 8 + h) * 32 + d) * 1024 + mc * 64 + m] = tile[m][d];
    }
}

// ---------------------------------------------------------------------------
// Flash attention v3: swapped-QK orientation, key-split across 4 waves.
// grid (32 q-tiles, 8 heads, 8 batches); block = 4 waves.
// ---------------------------------------------------------------------------
__global__ __launch_bounds__(256) void attn_kernel(
    const bf16* __restrict__ qh, const bf16* __restrict__ kvp, const bf16* __restrict__ vT,
    const bf16* __restrict__ biasF, bf16* __restrict__ attnout)
{
    __shared__ __align__(16) bf16 Ps[4][32 * 40];
    __shared__ __align__(16) __half accs[4][32][34];   // [w][d][q]
    __shared__ float pm[4][32], pl[4][32];
    const int tid = threadIdx.x, lane = tid & 63, wid = tid >> 6;
    const int lo = lane & 15, hi = lane >> 4;
    const int qt = blockIdx.x, n0 = qt * 32;
    const int h = blockIdx.y;
    const int b = blockIdx.z;
    const float scale = 0.17677669529663687f;  // 1/sqrt(32)
    const f32x4 zero4 = {0.f, 0.f, 0.f, 0.f};

    bf16x8 qf[2];
#pragma unroll
    for (int qj = 0; qj < 2; ++qj)
        qf[qj] = *(const bf16x8*)&qh[(size_t)(b * 1024 + n0 + qj * 16 + lo) * 256 + h * 32 + hi * 8];

    f32x4 acc[2][2];  // [di][qj]: out^T[d][q]
#pragma unroll
    for (int i = 0; i < 2; ++i)
#pragma unroll
        for (int j = 0; j < 2; ++j) acc[i][j] = zero4;
    float mrow[2] = {-1e30f, -1e30f}, lrow[2] = {0.f, 0.f};

    bf16* Pw = Ps[wid];

    for (int t = wid; t < 32; t += 4) {
        const int m0 = t * 32;
        bf16x8 kfr0 = *(const bf16x8*)&kvp[(size_t)(b * 1024 + m0 + lo) * 512 + h * 32 + hi * 8];
        bf16x8 kfr1 = *(const bf16x8*)&kvp[(size_t)(b * 1024 + m0 + 16 + lo) * 512 + h * 32 + hi * 8];
        bf16x8 va0 = *(const bf16x8*)&vT[(size_t)((b * 8 + h) * 32 + lo) * 1024 + m0 + hi * 8];
        bf16x8 va1 = *(const bf16x8*)&vT[(size_t)((b * 8 + h) * 32 + 16 + lo) * 1024 + m0 + hi * 8];
        size_t boff = (((size_t)(h * 32 + qt) * 32 + t) * 2 * 64 + lane) * 8;
        bf16x8 bv0 = *(const bf16x8*)&biasF[boff];
        bf16x8 bv1 = *(const bf16x8*)&biasF[boff + 512];

        f32x4 s[2][2];  // [kf][qj]
        s[0][0] = __builtin_amdgcn_mfma_f32_16x16x32_bf16(kfr0, qf[0], zero4, 0, 0, 0);
        s[0][1] = __builtin_amdgcn_mfma_f32_16x16x32_bf16(kfr0, qf[1], zero4, 0, 0, 0);
        s[1][0] = __builtin_amdgcn_mfma_f32_16x16x32_bf16(kfr1, qf[0], zero4, 0, 0, 0);
        s[1][1] = __builtin_amdgcn_mfma_f32_16x16x32_bf16(kfr1, qf[1], zero4, 0, 0, 0);
#pragma unroll
        for (int kf = 0; kf < 2; ++kf)
#pragma unroll
            for (int r = 0; r < 4; ++r) {
                s[kf][0][r] = s[kf][0][r] * scale + (float)bv0[kf * 4 + r];
                s[kf][1][r] = s[kf][1][r] * scale + (float)bv1[kf * 4 + r];
            }
#pragma unroll
        for (int qj = 0; qj < 2; ++qj) {
            float mx = fmaxf(fmaxf(fmaxf(s[0][qj][0], s[0][qj][1]), fmaxf(s[0][qj][2], s[0][qj][3])),
                             fmaxf(fmaxf(s[1][qj][0], s[1][qj][1]), fmaxf(s[1][qj][2], s[1][qj][3])));
            mx = fmaxf(mx, __shfl_xor(mx, 16));
            mx = fmaxf(mx, __shfl_xor(mx, 32));
            float mnew = fmaxf(mrow[qj], mx);
            float alpha = __expf(mrow[qj] - mnew);
            float rs = 0.f;
#pragma unroll
            for (int kf = 0; kf < 2; ++kf)
#pragma unroll
                for (int r = 0; r < 4; ++r) {
                    float p = __expf(s[kf][qj][r] - mnew);
                    s[kf][qj][r] = p;
                    rs += p;
                }
            rs += __shfl_xor(rs, 16);
            rs += __shfl_xor(rs, 32);
            lrow[qj] = lrow[qj] * alpha + rs;
            mrow[qj] = mnew;
#pragma unroll
            for (int di = 0; di < 2; ++di)
#pragma unroll
                for (int r = 0; r < 4; ++r) acc[di][qj][r] *= alpha;
        }
#pragma unroll
        for (int qj = 0; qj < 2; ++qj)
#pragma unroll
            for (int kf = 0; kf < 2; ++kf)
#pragma unroll
                for (int r = 0; r < 4; ++r)
                    Pw[(qj * 16 + lo) * 40 + kf * 16 + hi * 4 + r] = (bf16)s[kf][qj][r];
        bf16x8 pb0 = *(const bf16x8*)&Pw[lo * 40 + hi * 8];
        bf16x8 pb1 = *(const bf16x8*)&Pw[(16 + lo) * 40 + hi * 8];
        acc[0][0] = __builtin_amdgcn_mfma_f32_16x16x32_bf16(va0, pb0, acc[0][0], 0, 0, 0);
        acc[0][1] = __builtin_amdgcn_mfma_f32_16x16x32_bf16(va0, pb1, acc[0][1], 0, 0, 0);
        acc[1][0] = __builtin_amdgcn_mfma_f32_16x16x32_bf16(va1, pb0, acc[1][0], 0, 0, 0);
        acc[1][1] = __builtin_amdgcn_mfma_f32_16x16x32_bf16(va1, pb1, acc[1][1], 0, 0, 0);
    }
#pragma unroll
    for (int di = 0; di < 2; ++di)
#pragma unroll
        for (int qj = 0; qj < 2; ++qj)
#pragma unroll
            for (int r = 0; r < 4; ++r)
                accs[wid][di * 16 + hi * 4 + r][qj * 16 + lo] = __float2half(acc[di][qj][r]);
    if (hi == 0) {
#pragma unroll
        for (int qj = 0; qj < 2; ++qj) {
            pm[wid][qj * 16 + lo] = mrow[qj];
            pl[wid][qj * 16 + lo] = lrow[qj];
        }
    }
    __syncthreads();
    int q = tid >> 3, d0 = (tid & 7) * 4;
    float M = fmaxf(fmaxf(pm[0][q], pm[1][q]), fmaxf(pm[2][q], pm[3][q]));
    float f0 = __expf(pm[0][q] - M), f1 = __expf(pm[1][q] - M);
    float f2 = __expf(pm[2][q] - M), f3 = __expf(pm[3][q] - M);
    float inv = 1.f / (pl[0][q] * f0 + pl[1][q] * f1 + pl[2][q] * f2 + pl[3][q] * f3);
    bf16 tmp[4];
#pragma unroll
    for (int j = 0; j < 4; ++j) {
        int d = d0 + j;
        float o = f0 * (float)accs[0][d][q] + f1 * (float)accs[1][d][q] +
                  f2 * (float)accs[2][d][q] + f3 * (float)accs[3][d][q];
        tmp[j] = (bf16)(o * inv);
    }
    *(bf16x4*)&attnout[(size_t)(b * 1024 + n0 + q) * 256 + h * 32 + d0] = *(const bf16x4*)tmp;
}

// ---------------------------------------------------------------------------
// LayerNorm v2: 32 rows/block through LDS, coalesced transposed write.
// ysp[b][c][n] gets 128B contiguous chunks per thread. grid = 256.
// ---------------------------------------------------------------------------
__global__ __launch_bounds__(256) void ln_kernel(const float* __restrict__ z,
    const float* __restrict__ g, const float* __restrict__ bb, float* __restrict__ ysp)
{
    __shared__ float buf[32][260];
    const int tid = threadIdx.x;
    const int r0 = blockIdx.x * 32;
    const int wid = tid >> 6, lane = tid & 63;
#pragma unroll
    for (int p = 0; p < 8; ++p) {
        int f = p * 256 + tid;          // f4-chunk: 32 rows x 64 chunks
        int row = f >> 6, c4 = (f & 63) * 4;
        *(f4*)&buf[row][c4] = *(const f4*)&z[(size_t)(r0 + row) * 256 + c4];
    }
    __syncthreads();
#pragma unroll
    for (int rr = 0; rr < 8; ++rr) {
        int row = wid * 8 + rr;
        f4 x = *(const f4*)&buf[row][lane * 4];
        float s = x[0] + x[1] + x[2] + x[3];
#pragma unroll
        for (int d = 1; d < 64; d <<= 1) s += __shfl_xor(s, d);
        float mean = s * (1.f / 256.f);
        f4 dv = {x[0] - mean, x[1] - mean, x[2] - mean, x[3] - mean};
        float s2 = dv[0] * dv[0] + dv[1] * dv[1] + dv[2] * dv[2] + dv[3] * dv[3];
#pragma unroll
        for (int d = 1; d < 64; d <<= 1) s2 += __shfl_xor(s2, d);
        float rstd = rsqrtf(s2 * (1.f / 256.f) + 1e-5f);
        f4 o = {dv[0] * rstd, dv[1] * rstd, dv[2] * rstd, dv[3] * rstd};
        *(f4*)&buf[row][lane * 4] = o;
    }
    __syncthreads();
    float gc = g[tid], bc = bb[tid];
    int b = r0 >> 10, n0 = r0 & 1023;
    float* dst = &ysp[((size_t)(b * 256 + tid) << 10) + n0];
#pragma unroll
    for (int p = 0; p < 8; ++p) {
        f4 o;
#pragma unroll
        for (int k = 0; k < 4; ++k) o[k] = buf[p * 4 + k][tid] * gc + bc;
        *(f4*)&dst[p * 4] = o;
    }
}

// ---------------------------------------------------------------------------
// Bilinear 32x32 -> 128x128 (align_corners=False, edge clamp) + ReLU + x.
// ---------------------------------------------------------------------------
__global__ __launch_bounds__(256) void upsample_kernel(const float* __restrict__ x,
    const float* __restrict__ ysp, float* __restrict__ out)
{
    int idx = blockIdx.x * 256 + threadIdx.x;
    int w4 = idx & 31; int r1 = idx >> 5;
    int hh = r1 & 127; int r2 = r1 >> 7;
    int c = r2 & 255; int b = r2 >> 8;
    float chh = 0.25f * hh - 0.375f;
    float fi = floorf(chh);
    float fh = chh - fi;
    int i0 = (int)fi;
    int ia = i0 < 0 ? 0 : i0;
    int ib = (i0 + 1) > 31 ? 31 : (i0 + 1);
    const float* yr = ysp + ((size_t)(b * 256 + c) << 10);
    const float* ra = yr + ia * 32;
    const float* rb = yr + ib * 32;
    f4 xv = *(const f4*)&x[(size_t)idx * 4];
    f4 o;
#pragma unroll
    for (int k = 0; k < 4; ++k) {
        int ww = w4 * 4 + k;
        float cww = 0.25f * ww - 0.375f;
        float fj = floorf(cww);
        float fw = cww - fj;
        int j0 = (int)fj;
        int ja = j0 < 0 ? 0 : j0;
        int jb = (j0 + 1) > 31 ? 31 : (j0 + 1);
        float v = (1.f - fh) * ((1.f - fw) * ra[ja] + fw * ra[jb]) +
                  fh * ((1.f - fw) * rb[ja] + fw * rb[jb]);
        o[k] = xv[k] + fmaxf(v, 0.f);
    }
    *(f4*)&out[(size_t)idx * 4] = o;
}

// ---------------------------------------------------------------------------
extern "C" void kernel_launch(void* const* d_in, const int* in_sizes, int n_in,
                              void* d_out, int out_size, void* d_ws, size_t ws_size,
                              hipStream_t stream)
{
    (void)n_in; (void)out_size; (void)ws_size;
    const float* q    = (const float*)d_in[0];
    const float* kv   = (const float*)d_in[1];
    const int*   ridx = (const int*)d_in[2];
    const float* rtab = (const float*)d_in[3];
    const float* Wq   = (const float*)d_in[4];
    const float* bq   = (const float*)d_in[5];
    const float* Wkv  = (const float*)d_in[6];
    const float* bkv  = (const float*)d_in[7];
    const float* Wo   = (const float*)d_in[8];
    const float* bo   = (const float*)d_in[9];
    const float* cw1  = (const float*)d_in[10];
    const float* cb1  = (const float*)d_in[11];
    const float* cw2  = (const float*)d_in[12];
    const float* cb2  = (const float*)d_in[13];
    const float* fw1  = (const float*)d_in[14];
    const float* fb1  = (const float*)d_in[15];
    const float* fw2  = (const float*)d_in[16];
    const float* fb2  = (const float*)d_in[17];
    const float* lng  = (const float*)d_in[18];
    const float* lnb  = (const float*)d_in[19];
    const int L = in_sizes[3] / 2;   // rel_coords_table is [L][2]

    char* w = (char*)d_ws;
    auto alloc = [&](size_t bytes) { char* p = w; w += (bytes + 255) & ~(size_t)255; return p; };
    bf16* qt      = (bf16*)alloc(8192ull * 256 * 2);
    bf16* kvt     = (bf16*)alloc(8192ull * 256 * 2);
    bf16* qhb     = (bf16*)alloc(8192ull * 256 * 2);
    bf16* kvpb    = (bf16*)alloc(8192ull * 512 * 2);
    bf16* vTb     = (bf16*)alloc(8ull * 8 * 32 * 1024 * 2);
    bf16* attnb   = (bf16*)alloc(8192ull * 256 * 2);
    bf16* outb    = (bf16*)alloc(8192ull * 256 * 2);
    bf16* ffh     = (bf16*)alloc(8192ull * 1024 * 2);   // aliased: biasF before FFN1
    float* z      = (float*)alloc(8192ull * 256 * 4);
    float* ysp    = (float*)alloc(8192ull * 256 * 4);
    bf16* WqT     = (bf16*)alloc(256ull * 256 * 2);
    bf16* WkvT    = (bf16*)alloc(512ull * 256 * 2);
    bf16* WoT     = (bf16*)alloc(256ull * 256 * 2);
    bf16* W1T     = (bf16*)alloc(1024ull * 256 * 2);
    bf16* W2T     = (bf16*)alloc(256ull * 1024 * 2);
    float* cpbb   = (float*)alloc((size_t)8 * L * 4);
    bf16* biasF   = ffh;   // 16.78 MB, dead before ffh is first written

    wtrans_all<<<dim3(3072), 256, 0, stream>>>(Wq, Wkv, Wo, fw1, fw2, WqT, WkvT, WoT, W1T, W2T);
    cpb_kernel<<<dim3((L + 31) / 32), 256, 0, stream>>>(rtab, cw1, cb1, cw2, cb2, cpbb, L);
    bias_gather_kernel<<<dim3(256), 256, 0, stream>>>(ridx, cpbb, biasF, L);
    downsample_kernel<<<dim3(4096), 256, 0, stream>>>(q, kv, qt, kvt);
    // qh = qt @ Wq + bq
    gemm_bt<64, 64><<<dim3(128, 4), 256, 0, stream>>>(qt, WqT, bq, qhb, nullptr, nullptr, 8192, 256, 256, 0);
    // kvproj = kvt @ Wkv + bkv
    gemm_bt<64, 64><<<dim3(128, 8), 256, 0, stream>>>(kvt, WkvT, bkv, kvpb, nullptr, nullptr, 8192, 512, 256, 0);
    vtrans_kernel<<<dim3(1024), 256, 0, stream>>>(kvpb, vTb);
    attn_kernel<<<dim3(32, 8, 8), 256, 0, stream>>>(qhb, kvpb, vTb, biasF, attnb);
    // out = attn @ Wo + bo
    gemm_bt<64, 64><<<dim3(128, 4), 256, 0, stream>>>(attnb, WoT, bo, outb, nullptr, nullptr, 8192, 256, 256, 0);
    // ffh = gelu(out @ ffn_w1 + b1)   (overwrites biasF — attn is done)
    gemm_bt<128, 64><<<dim3(64, 16), 256, 0, stream>>>(outb, W1T, fb1, ffh, nullptr, nullptr, 8192, 1024, 256, 1);
    // z = ffh @ ffn_w2 + b2 + out  (fp32)
    gemm_bt<64, 64><<<dim3(128, 4), 256, 0, stream>>>(ffh, W2T, fb2, nullptr, z, outb, 8192, 256, 1024, 0);
    ln_kernel<<<dim3(256), 256, 0, stream>>>(z, lng, lnb, ysp);
    upsample_kernel<<<dim3(32768), 256, 0, stream>>>(q, ysp, (float*)d_out);
}

// Round 4
// 199.292 us; speedup vs baseline: 2.5316x; 1.1096x over previous
//
#include <hip/hip_runtime.h>
#include <hip/hip_bf16.h>
#include <hip/hip_fp16.h>

typedef __hip_bfloat16 bf16;
typedef __attribute__((ext_vector_type(8))) __bf16 bf16x8;   // 8 bf16 = 4 VGPRs (MFMA A/B frag)
typedef __attribute__((ext_vector_type(4))) __bf16 bf16x4;   // 8B packed store
typedef __attribute__((ext_vector_type(4))) float f32x4;     // MFMA C/D frag
typedef __attribute__((ext_vector_type(4))) float f4;        // indexable float4

// async global->LDS, 16B per lane. LDS dest must be wave-uniform base (lane*16 auto).
__device__ __forceinline__ void gload_lds16(const bf16* g, bf16* l)
{
    __builtin_amdgcn_global_load_lds((const __attribute__((address_space(1))) void*)g,
                                     (__attribute__((address_space(3))) void*)l, 16, 0, 0);
}

// ---------------------------------------------------------------------------
// prep_kernel: fuses (a) CPB MLP, (b) 5 weight transposes, (c) both
// downsamples. Branch by block range; whole block takes one path.
// grid = ncpb + 3072 + 4096.
// ---------------------------------------------------------------------------
__global__ __launch_bounds__(256) void prep_kernel(
    // cpb
    const float* __restrict__ tab, const float* __restrict__ w1, const float* __restrict__ b1,
    const float* __restrict__ w2, const float* __restrict__ b2, float* __restrict__ cpbout, int L, int ncpb,
    // wtrans
    const float* __restrict__ Wq, const float* __restrict__ Wkv, const float* __restrict__ Wo,
    const float* __restrict__ fw1, const float* __restrict__ fw2,
    bf16* __restrict__ WqT, bf16* __restrict__ WkvT, bf16* __restrict__ WoT,
    bf16* __restrict__ W1T, bf16* __restrict__ W2T,
    // downsample
    const float* __restrict__ qsrc, const float* __restrict__ kvsrc,
    bf16* __restrict__ qdst, bf16* __restrict__ kvdst)
{
    __shared__ float o[32][33];
    const int t = threadIdx.x;
    int bid = blockIdx.x;
    if (bid < ncpb) {
        // ---- CPB MLP: 8 threads per l, shuffle-reduced ----
        int l = bid * 32 + (t >> 3);
        int js = t & 7;
        bool valid = l < L;
        float t0 = valid ? tab[2 * l] : 0.f, t1 = valid ? tab[2 * l + 1] : 0.f;
        float acc[8];
#pragma unroll
        for (int hh = 0; hh < 8; ++hh) acc[hh] = 0.f;
        for (int j = js; j < 512; j += 8) {
            float hv = fmaxf(t0 * w1[j] + t1 * w1[512 + j] + b1[j], 0.f);
            f4 w2a = *(const f4*)&w2[j * 8];
            f4 w2b = *(const f4*)&w2[j * 8 + 4];
#pragma unroll
            for (int hh = 0; hh < 4; ++hh) { acc[hh] += hv * w2a[hh]; acc[4 + hh] += hv * w2b[hh]; }
        }
#pragma unroll
        for (int d = 1; d < 8; d <<= 1)
#pragma unroll
            for (int hh = 0; hh < 8; ++hh) acc[hh] += __shfl_xor(acc[hh], d);
        if (js == 0 && valid)
#pragma unroll
            for (int hh = 0; hh < 8; ++hh) cpbout[(size_t)hh * L + l] = acc[hh] + b2[hh];
        return;
    }
    bid -= ncpb;
    if (bid < 3072) {
        // ---- weight transpose: WT[n][k] = bf16(W[k][n]) ----
        const float* W; bf16* WT; int K, N, base;
        if (bid < 256)       { W = Wq;  WT = WqT;  K = 256;  N = 256;  base = 0; }
        else if (bid < 768)  { W = Wkv; WT = WkvT; K = 256;  N = 512;  base = 256; }
        else if (bid < 1024) { W = Wo;  WT = WoT;  K = 256;  N = 256;  base = 768; }
        else if (bid < 2048) { W = fw1; WT = W1T;  K = 256;  N = 1024; base = 1024; }
        else                 { W = fw2; WT = W2T;  K = 1024; N = 256;  base = 2048; }
        int idx = (bid - base) * 256 + t;
        int n = idx / K, k = idx % K;
        WT[idx] = (bf16)W[(size_t)k * N + n];
        return;
    }
    bid -= 3072;
    {
        // ---- downsample 128->32 + ReLU -> bf16 [B*1024][256] ----
        const float* src = bid < 2048 ? qsrc : kvsrc;
        bf16* dst = bid < 2048 ? qdst : kvdst;
        int bb2 = bid & 2047;
        int cc = bb2 & 7, i = (bb2 >> 3) & 31, b = bb2 >> 8;
#pragma unroll
        for (int p = 0; p < 4; ++p) {
            int id = p * 256 + t;
            int c = id >> 5, j = id & 31;
            const float* r = src + ((size_t)(b * 256 + cc * 32 + c) * 128 + 4 * i + 1) * 128 + 4 * j;
            float4 r1 = *(const float4*)r;
            float4 r2 = *(const float4*)(r + 128);
            o[c][j] = 0.25f * (r1.y + r1.z + r2.y + r2.z);
        }
        __syncthreads();
#pragma unroll
        for (int p = 0; p < 4; ++p) {
            int id = p * 256 + t;
            int j = id >> 5, c = id & 31;
            dst[(size_t)(b * 1024 + i * 32 + j) * 256 + cc * 32 + c] = (bf16)fmaxf(o[c][j], 0.f);
        }
    }
}

// ---------------------------------------------------------------------------
// Fragment-ordered bias gather: biasF[h][qt][mt][qj][lane][8] (bf16), matching
// the C/D layout of s[kf][qj] = mfma(Kfrag, Qfrag).
// ---------------------------------------------------------------------------
__global__ __launch_bounds__(256) void bias_gather_kernel(
    const int* __restrict__ ridx, const float* __restrict__ cpbh,
    bf16* __restrict__ biasF, int L)
{
    int gid = blockIdx.x * 256 + threadIdx.x;
    int ls = gid & 63;
    int mt = (gid >> 6) & 31;
    int qt = gid >> 11;
    int lo = ls & 15, hi = ls >> 4;
    int idx[2][8];
#pragma unroll
    for (int qj = 0; qj < 2; ++qj)
#pragma unroll
        for (int j = 0; j < 8; ++j) {
            int kf = j >> 2, r = j & 3;
            int q = qt * 32 + qj * 16 + lo;
            int m = mt * 32 + kf * 16 + hi * 4 + r;
            idx[qj][j] = ridx[q * 1024 + m];
        }
    for (int h = 0; h < 8; ++h) {
        const float* ct = cpbh + (size_t)h * L;
#pragma unroll
        for (int qj = 0; qj < 2; ++qj) {
            bf16 vals[8];
#pragma unroll
            for (int j = 0; j < 8; ++j) vals[j] = (bf16)ct[idx[qj][j]];
            size_t off = ((((size_t)(h * 32 + qt) * 32 + mt) * 2 + qj) * 64 + ls) * 8;
            *(bf16x8*)&biasF[off] = *(const bf16x8*)vals;
        }
    }
}

// ---------------------------------------------------------------------------
// GEMM v4: C[M][N] = act(A[M][K] @ BT[N][K]^T + bias) (+resid)
// Tile BM x BN, BK=64, 4 waves (2x2), wave tile (BM/2 x BN/2).
// Staging via async global_load_lds (linear LDS dest, XOR-swizzled global
// source: chunk cs holds data chunk cs^(row&7)) -> <=2-way LDS conflicts.
// ---------------------------------------------------------------------------
template<int BM, int BN>
__global__ __launch_bounds__(256) void gemm_bt(
    const bf16* __restrict__ A, const bf16* __restrict__ BT,
    const float* __restrict__ bias, bf16* __restrict__ Cb, float* __restrict__ Cf,
    const bf16* __restrict__ resid, int M, int N, int K, int act)
{
    constexpr int MI = BM / 32;   // row frags per wave
    constexpr int NJ = BN / 32;   // col frags per wave
    __shared__ __align__(16) bf16 As[BM * 64];
    __shared__ __align__(16) bf16 Bs[BN * 64];
    const int tid = threadIdx.x;
    const int lane = tid & 63, wid = tid >> 6;
    const int lo = lane & 15, hi = lane >> 4;
    const int m0 = blockIdx.x * BM, n0 = blockIdx.y * BN;
    const int wr = wid >> 1, wc = wid & 1;
    f32x4 acc[MI][NJ];
#pragma unroll
    for (int i = 0; i < MI; ++i)
#pragma unroll
        for (int j = 0; j < NJ; ++j) acc[i][j] = f32x4{0.f, 0.f, 0.f, 0.f};

    for (int k0 = 0; k0 < K; k0 += 64) {
        __syncthreads();
#pragma unroll
        for (int p = 0; p < BM / 32; ++p) {
            int f = p * 256 + wid * 64 + lane;
            int row = f >> 3, cs = f & 7;
            gload_lds16(&A[(size_t)(m0 + row) * K + k0 + ((cs ^ (row & 7)) * 8)],
                        As + (size_t)(p * 256 + wid * 64) * 8);
        }
#pragma unroll
        for (int p = 0; p < BN / 32; ++p) {
            int f = p * 256 + wid * 64 + lane;
            int row = f >> 3, cs = f & 7;
            gload_lds16(&BT[(size_t)(n0 + row) * K + k0 + ((cs ^ (row & 7)) * 8)],
                        Bs + (size_t)(p * 256 + wid * 64) * 8);
        }
        __syncthreads();   // drains vmcnt(0) for global_load_lds
        bf16x8 af[2][MI], bfr[2][NJ];
#pragma unroll
        for (int kk = 0; kk < 2; ++kk) {
#pragma unroll
            for (int i = 0; i < MI; ++i) {
                int row = wr * (BM / 2) + i * 16 + lo;
                af[kk][i] = *(const bf16x8*)&As[row * 64 + (((kk * 4 + hi) ^ (lo & 7)) * 8)];
            }
#pragma unroll
            for (int j = 0; j < NJ; ++j) {
                int row = wc * (BN / 2) + j * 16 + lo;
                bfr[kk][j] = *(const bf16x8*)&Bs[row * 64 + (((kk * 4 + hi) ^ (lo & 7)) * 8)];
            }
        }
#pragma unroll
        for (int kk = 0; kk < 2; ++kk)
#pragma unroll
            for (int i = 0; i < MI; ++i)
#pragma unroll
                for (int j = 0; j < NJ; ++j)
                    acc[i][j] = __builtin_amdgcn_mfma_f32_16x16x32_bf16(af[kk][i], bfr[kk][j], acc[i][j], 0, 0, 0);
    }
#pragma unroll
    for (int i = 0; i < MI; ++i)
#pragma unroll
        for (int j = 0; j < NJ; ++j) {
            int col = n0 + wc * (BN / 2) + j * 16 + lo;
            float bv = bias[col];
#pragma unroll
            for (int r = 0; r < 4; ++r) {
                int row = m0 + wr * (BM / 2) + i * 16 + hi * 4 + r;
                float v = acc[i][j][r] + bv;
                if (act == 1) v = 0.5f * v * (1.f + erff(v * 0.70710678118654752f));
                if (resid) v += (float)resid[(size_t)row * N + col];
                if (Cb) Cb[(size_t)row * N + col] = (bf16)v;
                else    Cf[(size_t)row * N + col] = v;
            }
        }
}

// ---------------------------------------------------------------------------
// FFN2 + residual + LayerNorm + transpose, fused.
// z_row = ffh[row] @ W2T^T + fb2 + outb[row]; y = LN(z_row)*g+b;
// ysp[b][c][n] = bf16(y[c]) for row = b*1024+n.
// Tile 32 x 256 (BN = full row), K=1024, BK=64, 4 waves (1x4). grid = 256.
// ---------------------------------------------------------------------------
__global__ __launch_bounds__(256) void ffn2_ln_kernel(
    const bf16* __restrict__ A, const bf16* __restrict__ BT,
    const float* __restrict__ bias, const bf16* __restrict__ resid,
    const float* __restrict__ g, const float* __restrict__ bb,
    bf16* __restrict__ ysp)
{
    __shared__ __align__(16) bf16 As[32 * 64];
    __shared__ __align__(16) bf16 Bs[256 * 64];
    __shared__ float buf[32][260];
    const int tid = threadIdx.x;
    const int lane = tid & 63, wid = tid >> 6;
    const int lo = lane & 15, hi = lane >> 4;
    const int m0 = blockIdx.x * 32;
    f32x4 acc[2][4];
#pragma unroll
    for (int i = 0; i < 2; ++i)
#pragma unroll
        for (int j = 0; j < 4; ++j) acc[i][j] = f32x4{0.f, 0.f, 0.f, 0.f};

    for (int k0 = 0; k0 < 1024; k0 += 64) {
        __syncthreads();
        {   // A: 32 rows x 8 chunks = 256 lanes
            int f = tid;
            int row = f >> 3, cs = f & 7;
            gload_lds16(&A[(size_t)(m0 + row) * 1024 + k0 + ((cs ^ (row & 7)) * 8)],
                        As + (size_t)(wid * 64) * 8);
        }
#pragma unroll
        for (int p = 0; p < 8; ++p) {   // B: 256 rows x 8 chunks
            int f = p * 256 + tid;
            int row = f >> 3, cs = f & 7;
            gload_lds16(&BT[(size_t)row * 1024 + k0 + ((cs ^ (row & 7)) * 8)],
                        Bs + (size_t)(p * 256 + wid * 64) * 8);
        }
        __syncthreads();
        bf16x8 af[2][2], bfr[2][4];
#pragma unroll
        for (int kk = 0; kk < 2; ++kk) {
#pragma unroll
            for (int i = 0; i < 2; ++i) {
                int row = i * 16 + lo;
                af[kk][i] = *(const bf16x8*)&As[row * 64 + (((kk * 4 + hi) ^ (lo & 7)) * 8)];
            }
#pragma unroll
            for (int j = 0; j < 4; ++j) {
                int row = wid * 64 + j * 16 + lo;
                bfr[kk][j] = *(const bf16x8*)&Bs[row * 64 + (((kk * 4 + hi) ^ (lo & 7)) * 8)];
            }
        }
#pragma unroll
        for (int kk = 0; kk < 2; ++kk)
#pragma unroll
            for (int i = 0; i < 2; ++i)
#pragma unroll
                for (int j = 0; j < 4; ++j)
                    acc[i][j] = __builtin_amdgcn_mfma_f32_16x16x32_bf16(af[kk][i], bfr[kk][j], acc[i][j], 0, 0, 0);
    }
    // epilogue: z = acc + bias + resid -> buf[row][col]
#pragma unroll
    for (int i = 0; i < 2; ++i)
#pragma unroll
        for (int j = 0; j < 4; ++j) {
            int col = wid * 64 + j * 16 + lo;
            float bv = bias[col];
#pragma unroll
            for (int r = 0; r < 4; ++r) {
                int lr = i * 16 + hi * 4 + r;
                buf[lr][col] = acc[i][j][r] + bv + (float)resid[(size_t)(m0 + lr) * 256 + col];
            }
        }
    __syncthreads();
    // LN per row (each wave: 8 rows, 64 lanes x 4 cols)
#pragma unroll
    for (int rr = 0; rr < 8; ++rr) {
        int row = wid * 8 + rr;
        f4 x = *(const f4*)&buf[row][lane * 4];
        float s = x[0] + x[1] + x[2] + x[3];
#pragma unroll
        for (int d = 1; d < 64; d <<= 1) s += __shfl_xor(s, d);
        float mean = s * (1.f / 256.f);
        f4 dv = {x[0] - mean, x[1] - mean, x[2] - mean, x[3] - mean};
        float s2 = dv[0] * dv[0] + dv[1] * dv[1] + dv[2] * dv[2] + dv[3] * dv[3];
#pragma unroll
        for (int d = 1; d < 64; d <<= 1) s2 += __shfl_xor(s2, d);
        float rstd = rsqrtf(s2 * (1.f / 256.f) + 1e-5f);
        f4 o = {dv[0] * rstd, dv[1] * rstd, dv[2] * rstd, dv[3] * rstd};
        *(f4*)&buf[row][lane * 4] = o;
    }
    __syncthreads();
    // transposed write: thread = channel c, 32 n-values contiguous (bf16)
    float gc = g[tid], bc = bb[tid];
    int b = m0 >> 10, n0l = m0 & 1023;
    bf16* dst = &ysp[((size_t)(b * 256 + tid) << 10) + n0l];
#pragma unroll
    for (int p = 0; p < 4; ++p) {
        bf16 tmp[8];
#pragma unroll
        for (int k = 0; k < 8; ++k) tmp[k] = (bf16)(buf[p * 8 + k][tid] * gc + bc);
        *(bf16x8*)&dst[p * 8] = *(const bf16x8*)tmp;
    }
}

// ---------------------------------------------------------------------------
// V transpose: vT[b][h][d][m] = kvproj[b*1024+m][256 + h*32 + d]  (bf16)
// ---------------------------------------------------------------------------
__global__ __launch_bounds__(256) void vtrans_kernel(const bf16* __restrict__ kvp,
                                                     bf16* __restrict__ vT)
{
    __shared__ __align__(16) bf16 tile[64][40];
    int bid = blockIdx.x;
    int mc = bid & 15, h = (bid >> 4) & 7, b = bid >> 7;
    int t = threadIdx.x;
    {
        int m = t >> 2, p = (t & 3) * 8;
        *(float4*)&tile[m][p] =
            *(const float4*)&kvp[(size_t)(b * 1024 + mc * 64 + m) * 512 + 256 + h * 32 + p];
    }
    __syncthreads();
#pragma unroll
    for (int it = 0; it < 8; ++it) {
        int f = it * 256 + t;
        int d = f >> 6, m = f & 63;
        vT[(size_t)((b * 8 + h) * 32 + d) * 1024 + mc * 64 + m] = tile[m][d];
    }
}

// ---------------------------------------------------------------------------
// Flash attention v3: swapped-QK orientation, key-split across 4 waves.
// grid (32 q-tiles, 8 heads, 8 batches); block = 4 waves.
// ---------------------------------------------------------------------------
__global__ __launch_bounds__(256) void attn_kernel(
    const bf16* __restrict__ qh, const bf16* __restrict__ kvp, const bf16* __restrict__ vT,
    const bf16* __restrict__ biasF, bf16* __restrict__ attnout)
{
    __shared__ __align__(16) bf16 Ps[4][32 * 40];
    __shared__ __align__(16) __half accs[4][32][34];   // [w][d][q]
    __shared__ float pm[4][32], pl[4][32];
    const int tid = threadIdx.x, lane = tid & 63, wid = tid >> 6;
    const int lo = lane & 15, hi = lane >> 4;
    const int qt = blockIdx.x, n0 = qt * 32;
    const int h = blockIdx.y;
    const int b = blockIdx.z;
    const float scale = 0.17677669529663687f;  // 1/sqrt(32)
    const f32x4 zero4 = {0.f, 0.f, 0.f, 0.f};

    bf16x8 qf[2];
#pragma unroll
    for (int qj = 0; qj < 2; ++qj)
        qf[qj] = *(const bf16x8*)&qh[(size_t)(b * 1024 + n0 + qj * 16 + lo) * 256 + h * 32 + hi * 8];

    f32x4 acc[2][2];  // [di][qj]: out^T[d][q]
#pragma unroll
    for (int i = 0; i < 2; ++i)
#pragma unroll
        for (int j = 0; j < 2; ++j) acc[i][j] = zero4;
    float mrow[2] = {-1e30f, -1e30f}, lrow[2] = {0.f, 0.f};

    bf16* Pw = Ps[wid];

    for (int t = wid; t < 32; t += 4) {
        const int m0 = t * 32;
        bf16x8 kfr0 = *(const bf16x8*)&kvp[(size_t)(b * 1024 + m0 + lo) * 512 + h * 32 + hi * 8];
        bf16x8 kfr1 = *(const bf16x8*)&kvp[(size_t)(b * 1024 + m0 + 16 + lo) * 512 + h * 32 + hi * 8];
        bf16x8 va0 = *(const bf16x8*)&vT[(size_t)((b * 8 + h) * 32 + lo) * 1024 + m0 + hi * 8];
        bf16x8 va1 = *(const bf16x8*)&vT[(size_t)((b * 8 + h) * 32 + 16 + lo) * 1024 + m0 + hi * 8];
        size_t boff = (((size_t)(h * 32 + qt) * 32 + t) * 2 * 64 + lane) * 8;
        bf16x8 bv0 = *(const bf16x8*)&biasF[boff];
        bf16x8 bv1 = *(const bf16x8*)&biasF[boff + 512];

        f32x4 s[2][2];  // [kf][qj]
        s[0][0] = __builtin_amdgcn_mfma_f32_16x16x32_bf16(kfr0, qf[0], zero4, 0, 0, 0);
        s[0][1] = __builtin_amdgcn_mfma_f32_16x16x32_bf16(kfr0, qf[1], zero4, 0, 0, 0);
        s[1][0] = __builtin_amdgcn_mfma_f32_16x16x32_bf16(kfr1, qf[0], zero4, 0, 0, 0);
        s[1][1] = __builtin_amdgcn_mfma_f32_16x16x32_bf16(kfr1, qf[1], zero4, 0, 0, 0);
#pragma unroll
        for (int kf = 0; kf < 2; ++kf)
#pragma unroll
            for (int r = 0; r < 4; ++r) {
                s[kf][0][r] = s[kf][0][r] * scale + (float)bv0[kf * 4 + r];
                s[kf][1][r] = s[kf][1][r] * scale + (float)bv1[kf * 4 + r];
            }
#pragma unroll
        for (int qj = 0; qj < 2; ++qj) {
            float mx = fmaxf(fmaxf(fmaxf(s[0][qj][0], s[0][qj][1]), fmaxf(s[0][qj][2], s[0][qj][3])),
                             fmaxf(fmaxf(s[1][qj][0], s[1][qj][1]), fmaxf(s[1][qj][2], s[1][qj][3])));
            mx = fmaxf(mx, __shfl_xor(mx, 16));
            mx = fmaxf(mx, __shfl_xor(mx, 32));
            float mnew = fmaxf(mrow[qj], mx);
            float alpha = __expf(mrow[qj] - mnew);
            float rs = 0.f;
#pragma unroll
            for (int kf = 0; kf < 2; ++kf)
#pragma unroll
                for (int r = 0; r < 4; ++r) {
                    float p = __expf(s[kf][qj][r] - mnew);
                    s[kf][qj][r] = p;
                    rs += p;
                }
            rs += __shfl_xor(rs, 16);
            rs += __shfl_xor(rs, 32);
            lrow[qj] = lrow[qj] * alpha + rs;
            mrow[qj] = mnew;
#pragma unroll
            for (int di = 0; di < 2; ++di)
#pragma unroll
                for (int r = 0; r < 4; ++r) acc[di][qj][r] *= alpha;
        }
#pragma unroll
        for (int qj = 0; qj < 2; ++qj)
#pragma unroll
            for (int kf = 0; kf < 2; ++kf)
#pragma unroll
                for (int r = 0; r < 4; ++r)
                    Pw[(qj * 16 + lo) * 40 + kf * 16 + hi * 4 + r] = (bf16)s[kf][qj][r];
        bf16x8 pb0 = *(const bf16x8*)&Pw[lo * 40 + hi * 8];
        bf16x8 pb1 = *(const bf16x8*)&Pw[(16 + lo) * 40 + hi * 8];
        acc[0][0] = __builtin_amdgcn_mfma_f32_16x16x32_bf16(va0, pb0, acc[0][0], 0, 0, 0);
        acc[0][1] = __builtin_amdgcn_mfma_f32_16x16x32_bf16(va0, pb1, acc[0][1], 0, 0, 0);
        acc[1][0] = __builtin_amdgcn_mfma_f32_16x16x32_bf16(va1, pb0, acc[1][0], 0, 0, 0);
        acc[1][1] = __builtin_amdgcn_mfma_f32_16x16x32_bf16(va1, pb1, acc[1][1], 0, 0, 0);
    }
#pragma unroll
    for (int di = 0; di < 2; ++di)
#pragma unroll
        for (int qj = 0; qj < 2; ++qj)
#pragma unroll
            for (int r = 0; r < 4; ++r)
                accs[wid][di * 16 + hi * 4 + r][qj * 16 + lo] = __float2half(acc[di][qj][r]);
    if (hi == 0) {
#pragma unroll
        for (int qj = 0; qj < 2; ++qj) {
            pm[wid][qj * 16 + lo] = mrow[qj];
            pl[wid][qj * 16 + lo] = lrow[qj];
        }
    }
    __syncthreads();
    int q = tid >> 3, d0 = (tid & 7) * 4;
    float M = fmaxf(fmaxf(pm[0][q], pm[1][q]), fmaxf(pm[2][q], pm[3][q]));
    float f0 = __expf(pm[0][q] - M), f1 = __expf(pm[1][q] - M);
    float f2 = __expf(pm[2][q] - M), f3 = __expf(pm[3][q] - M);
    float inv = 1.f / (pl[0][q] * f0 + pl[1][q] * f1 + pl[2][q] * f2 + pl[3][q] * f3);
    bf16 tmp[4];
#pragma unroll
    for (int j = 0; j < 4; ++j) {
        int d = d0 + j;
        float o = f0 * (float)accs[0][d][q] + f1 * (float)accs[1][d][q] +
                  f2 * (float)accs[2][d][q] + f3 * (float)accs[3][d][q];
        tmp[j] = (bf16)(o * inv);
    }
    *(bf16x4*)&attnout[(size_t)(b * 1024 + n0 + q) * 256 + h * 32 + d0] = *(const bf16x4*)tmp;
}

// ---------------------------------------------------------------------------
// Bilinear 32x32 -> 128x128 (align_corners=False, edge clamp) + ReLU + x.
// ysp is bf16 [B][C][1024].
// ---------------------------------------------------------------------------
__global__ __launch_bounds__(256) void upsample_kernel(const float* __restrict__ x,
    const bf16* __restrict__ ysp, float* __restrict__ out)
{
    int idx = blockIdx.x * 256 + threadIdx.x;
    int w4 = idx & 31; int r1 = idx >> 5;
    int hh = r1 & 127; int r2 = r1 >> 7;
    int c = r2 & 255; int b = r2 >> 8;
    float chh = 0.25f * hh - 0.375f;
    float fi = floorf(chh);
    float fh = chh - fi;
    int i0 = (int)fi;
    int ia = i0 < 0 ? 0 : i0;
    int ib = (i0 + 1) > 31 ? 31 : (i0 + 1);
    const bf16* yr = ysp + ((size_t)(b * 256 + c) << 10);
    const bf16* ra = yr + ia * 32;
    const bf16* rb = yr + ib * 32;
    f4 xv = *(const f4*)&x[(size_t)idx * 4];
    f4 o;
#pragma unroll
    for (int k = 0; k < 4; ++k) {
        int ww = w4 * 4 + k;
        float cww = 0.25f * ww - 0.375f;
        float fj = floorf(cww);
        float fw = cww - fj;
        int j0 = (int)fj;
        int ja = j0 < 0 ? 0 : j0;
        int jb = (j0 + 1) > 31 ? 31 : (j0 + 1);
        float v = (1.f - fh) * ((1.f - fw) * (float)ra[ja] + fw * (float)ra[jb]) +
                  fh * ((1.f - fw) * (float)rb[ja] + fw * (float)rb[jb]);
        o[k] = xv[k] + fmaxf(v, 0.f);
    }
    *(f4*)&out[(size_t)idx * 4] = o;
}

// ---------------------------------------------------------------------------
extern "C" void kernel_launch(void* const* d_in, const int* in_sizes, int n_in,
                              void* d_out, int out_size, void* d_ws, size_t ws_size,
                              hipStream_t stream)
{
    (void)n_in; (void)out_size; (void)ws_size;
    const float* q    = (const float*)d_in[0];
    const float* kv   = (const float*)d_in[1];
    const int*   ridx = (const int*)d_in[2];
    const float* rtab = (const float*)d_in[3];
    const float* Wq   = (const float*)d_in[4];
    const float* bq   = (const float*)d_in[5];
    const float* Wkv  = (const float*)d_in[6];
    const float* bkv  = (const float*)d_in[7];
    const float* Wo   = (const float*)d_in[8];
    const float* bo   = (const float*)d_in[9];
    const float* cw1  = (const float*)d_in[10];
    const float* cb1  = (const float*)d_in[11];
    const float* cw2  = (const float*)d_in[12];
    const float* cb2  = (const float*)d_in[13];
    const float* fw1  = (const float*)d_in[14];
    const float* fb1  = (const float*)d_in[15];
    const float* fw2  = (const float*)d_in[16];
    const float* fb2  = (const float*)d_in[17];
    const float* lng  = (const float*)d_in[18];
    const float* lnb  = (const float*)d_in[19];
    const int L = in_sizes[3] / 2;   // rel_coords_table is [L][2]
    const int ncpb = (L + 31) / 32;

    char* w = (char*)d_ws;
    auto alloc = [&](size_t bytes) { char* p = w; w += (bytes + 255) & ~(size_t)255; return p; };
    bf16* qt      = (bf16*)alloc(8192ull * 256 * 2);
    bf16* kvt     = (bf16*)alloc(8192ull * 256 * 2);
    bf16* qhb     = (bf16*)alloc(8192ull * 256 * 2);
    bf16* kvpb    = (bf16*)alloc(8192ull * 512 * 2);
    bf16* vTb     = (bf16*)alloc(8ull * 8 * 32 * 1024 * 2);
    bf16* attnb   = (bf16*)alloc(8192ull * 256 * 2);
    bf16* outb    = (bf16*)alloc(8192ull * 256 * 2);
    bf16* ffh     = (bf16*)alloc(8192ull * 1024 * 2);   // aliased: biasF before FFN1
    bf16* ysp     = (bf16*)alloc(8ull * 256 * 1024 * 2);
    bf16* WqT     = (bf16*)alloc(256ull * 256 * 2);
    bf16* WkvT    = (bf16*)alloc(512ull * 256 * 2);
    bf16* WoT     = (bf16*)alloc(256ull * 256 * 2);
    bf16* W1T     = (bf16*)alloc(1024ull * 256 * 2);
    bf16* W2T     = (bf16*)alloc(256ull * 1024 * 2);
    float* cpbb   = (float*)alloc((size_t)8 * L * 4);
    bf16* biasF   = ffh;   // 16.78 MB, dead before ffh is first written

    prep_kernel<<<dim3(ncpb + 3072 + 4096), 256, 0, stream>>>(
        rtab, cw1, cb1, cw2, cb2, cpbb, L, ncpb,
        Wq, Wkv, Wo, fw1, fw2, WqT, WkvT, WoT, W1T, W2T,
        q, kv, qt, kvt);
    bias_gather_kernel<<<dim3(256), 256, 0, stream>>>(ridx, cpbb, biasF, L);
    // qh = qt @ Wq + bq
    gemm_bt<64, 64><<<dim3(128, 4), 256, 0, stream>>>(qt, WqT, bq, qhb, nullptr, nullptr, 8192, 256, 256, 0);
    // kvproj = kvt @ Wkv + bkv
    gemm_bt<64, 64><<<dim3(128, 8), 256, 0, stream>>>(kvt, WkvT, bkv, kvpb, nullptr, nullptr, 8192, 512, 256, 0);
    vtrans_kernel<<<dim3(1024), 256, 0, stream>>>(kvpb, vTb);
    attn_kernel<<<dim3(32, 8, 8), 256, 0, stream>>>(qhb, kvpb, vTb, biasF, attnb);
    // out = attn @ Wo + bo
    gemm_bt<64, 64><<<dim3(128, 4), 256, 0, stream>>>(attnb, WoT, bo, outb, nullptr, nullptr, 8192, 256, 256, 0);
    // ffh = gelu(out @ ffn_w1 + b1)   (overwrites biasF — attn is done)
    gemm_bt<128, 64><<<dim3(64, 16), 256, 0, stream>>>(outb, W1T, fb1, ffh, nullptr, nullptr, 8192, 1024, 256, 1);
    // ysp = LN(ffh @ ffn_w2 + b2 + out) transposed, bf16
    ffn2_ln_kernel<<<dim3(256), 256, 0, stream>>>(ffh, W2T, fb2, outb, lng, lnb, ysp);
    upsample_kernel<<<dim3(32768), 256, 0, stream>>>(q, ysp, (float*)d_out);
}